// Round 1
// baseline (981.847 us; speedup 1.0000x reference)
//
#include <hip/hip_runtime.h>

#define B 8
#define N 1024
#define D 512
#define H 8
#define HD 64
#define M (B*N)          // 8192 rows
#define NEGF (-1e30f)

// ---------------------------------------------------------------------------
// Generic SGEMM: C[m,n] = sum_k A[m,k] * W[n,k] + bias[n]
// A row-major [Mdim,K], W row-major [Ndim,K] (torch-style weight), K==512 here.
// BM=128, BN=64, BK=16, 256 threads, 8x4 micro-tile.
// Pads: As stride 132 (132%32==4 -> 2-way max on staging, b128-aligned reads),
//       Bs stride 68.
// ---------------------------------------------------------------------------
__global__ __launch_bounds__(256) void gemm_bias(
    const float* __restrict__ A, const float* __restrict__ W,
    const float* __restrict__ bias, float* __restrict__ C,
    int Ndim, int K)
{
  __shared__ float As[16][132];   // [k][m]
  __shared__ float Bs[16][68];    // [k][n]
  const int tid  = threadIdx.x;
  const int row0 = blockIdx.y * 128;
  const int col0 = blockIdx.x * 64;
  const int ty = tid >> 4;        // 0..15 -> 8 rows each
  const int tx = tid & 15;        // 0..15 -> 4 cols each
  const int ra = tid >> 2;        // 0..63 staging row
  const int kq = (tid & 3) << 2;  // 0,4,8,12 staging k-offset

  float acc[8][4];
  #pragma unroll
  for (int i = 0; i < 8; ++i)
    #pragma unroll
    for (int j = 0; j < 4; ++j) acc[i][j] = 0.f;

  const float* Ap = A + (long)row0 * K;
  const float* Wp = W + (long)col0 * K;

  for (int k0 = 0; k0 < K; k0 += 16) {
    #pragma unroll
    for (int l = 0; l < 2; ++l) {          // A tile 128x16
      int r = ra + l * 64;
      float4 v = *(const float4*)(Ap + (long)r * K + k0 + kq);
      As[kq + 0][r] = v.x; As[kq + 1][r] = v.y;
      As[kq + 2][r] = v.z; As[kq + 3][r] = v.w;
    }
    {                                       // W tile 64x16
      float4 v = *(const float4*)(Wp + (long)ra * K + k0 + kq);
      Bs[kq + 0][ra] = v.x; Bs[kq + 1][ra] = v.y;
      Bs[kq + 2][ra] = v.z; Bs[kq + 3][ra] = v.w;
    }
    __syncthreads();
    #pragma unroll
    for (int k = 0; k < 16; ++k) {
      float a[8], bb[4];
      #pragma unroll
      for (int i = 0; i < 8; ++i) a[i] = As[k][ty * 8 + i];
      #pragma unroll
      for (int j = 0; j < 4; ++j) bb[j] = Bs[k][tx * 4 + j];
      #pragma unroll
      for (int i = 0; i < 8; ++i)
        #pragma unroll
        for (int j = 0; j < 4; ++j) acc[i][j] += a[i] * bb[j];
    }
    __syncthreads();
  }

  #pragma unroll
  for (int i = 0; i < 8; ++i) {
    int r = row0 + ty * 8 + i;
    int c = col0 + tx * 4;
    float4 v;
    v.x = acc[i][0] + bias[c + 0];
    v.y = acc[i][1] + bias[c + 1];
    v.z = acc[i][2] + bias[c + 2];
    v.w = acc[i][3] + bias[c + 3];
    *(float4*)(C + (long)r * Ndim + c) = v;
  }
}

// ---------------------------------------------------------------------------
// Fused masked attention, flash-style online softmax.
// Block = (b, h, 64-row q-tile); 256 threads as 16x16, 4x4 micro-tile.
// score = (head . tail) / sqrt(D);  masked -> -1e30; softmax; re-zero masked.
// Output written in [B,N,H*HD] layout so the comb GEMM consumes it directly.
// LDS pads = 68 floats (272B, 16B-aligned rows, <=2-way bank aliasing).
// ---------------------------------------------------------------------------
__global__ __launch_bounds__(256) void attn_fused(
    const float* __restrict__ head, const float* __restrict__ tail,
    const float* __restrict__ info, const int* __restrict__ graph,
    float* __restrict__ out)
{
  const int bh = blockIdx.y;
  const int b  = bh >> 3;
  const int h  = bh & 7;
  const int n0 = blockIdx.x * 64;
  const int tid = threadIdx.x;
  const int ty = tid >> 4;          // 0..15 -> rows ty*4 .. ty*4+3
  const int tx = tid & 15;          // 0..15 -> cols tx*4 .. tx*4+3
  const int rr = tid >> 4;          // staging: row group 0..15
  const int dr = (tid & 15) * 4;    // staging: dim offset

  __shared__ float Hs[64][68];  // [d][r]   head tile, transposed
  __shared__ float Ts[64][68];  // [d][c]   tail tile, transposed
  __shared__ float Vs[64][68];  // [c][d]   info tile, natural
  __shared__ float Ps[64][68];  // [r][c]   softmax weights

  const float* Hp = head + ((long)(b * N + n0)) * D + h * 64;
  const float* Tp = tail + ((long)b * N) * D + h * 64;
  const float* Vp = info + ((long)b * N) * D + h * 64;

  #pragma unroll
  for (int q = 0; q < 4; ++q) {     // load Hs once (transposed)
    int r = rr + q * 16;
    float4 v = *(const float4*)(Hp + (long)r * D + dr);
    Hs[dr + 0][r] = v.x; Hs[dr + 1][r] = v.y;
    Hs[dr + 2][r] = v.z; Hs[dr + 3][r] = v.w;
  }

  float o[4][4];
  #pragma unroll
  for (int i = 0; i < 4; ++i)
    #pragma unroll
    for (int j = 0; j < 4; ++j) o[i][j] = 0.f;
  float m_run[4], l_run[4];
  #pragma unroll
  for (int i = 0; i < 4; ++i) { m_run[i] = NEGF; l_run[i] = 0.f; }

  const float inv_scale = 0.04419417382415922f;  // 1/sqrt(512)

  for (int t = 0; t < 16; ++t) {
    const int m0 = t * 64;
    __syncthreads();                 // protect Ts/Vs/Ps from prev readers
    #pragma unroll
    for (int q = 0; q < 4; ++q) {    // stage Ts (transposed) and Vs (natural)
      int c = rr + q * 16;
      float4 v = *(const float4*)(Tp + (long)(m0 + c) * D + dr);
      Ts[dr + 0][c] = v.x; Ts[dr + 1][c] = v.y;
      Ts[dr + 2][c] = v.z; Ts[dr + 3][c] = v.w;
      float4 w = *(const float4*)(Vp + (long)(m0 + c) * D + dr);
      *(float4*)(&Vs[c][dr]) = w;
    }
    __syncthreads();

    // S tile: 4x4 per thread over d=0..63
    float s[4][4];
    #pragma unroll
    for (int i = 0; i < 4; ++i)
      #pragma unroll
      for (int j = 0; j < 4; ++j) s[i][j] = 0.f;
    #pragma unroll 16
    for (int d = 0; d < 64; ++d) {
      float a[4], bb[4];
      #pragma unroll
      for (int i = 0; i < 4; ++i) a[i]  = Hs[d][ty * 4 + i];
      #pragma unroll
      for (int j = 0; j < 4; ++j) bb[j] = Ts[d][tx * 4 + j];
      #pragma unroll
      for (int i = 0; i < 4; ++i)
        #pragma unroll
        for (int j = 0; j < 4; ++j) s[i][j] += a[i] * bb[j];
    }

    // mask + online softmax per row
    #pragma unroll
    for (int i = 0; i < 4; ++i) {
      const int4 g = *(const int4*)(graph +
          ((long)b * N + (n0 + ty * 4 + i)) * N + m0 + tx * 4);
      float s0 = g.x ? s[i][0] * inv_scale : NEGF;
      float s1 = g.y ? s[i][1] * inv_scale : NEGF;
      float s2 = g.z ? s[i][2] * inv_scale : NEGF;
      float s3 = g.w ? s[i][3] * inv_scale : NEGF;
      float rmax = fmaxf(fmaxf(s0, s1), fmaxf(s2, s3));
      rmax = fmaxf(rmax, __shfl_xor(rmax, 1, 16));
      rmax = fmaxf(rmax, __shfl_xor(rmax, 2, 16));
      rmax = fmaxf(rmax, __shfl_xor(rmax, 4, 16));
      rmax = fmaxf(rmax, __shfl_xor(rmax, 8, 16));
      const float mnew = fmaxf(m_run[i], rmax);
      const float fac  = __expf(m_run[i] - mnew);
      // explicit zero for masked entries (matches reference re-mask; also
      // avoids exp(0)=1 garbage while the running max is still -1e30)
      float p0 = (s0 <= -5e29f) ? 0.f : __expf(s0 - mnew);
      float p1 = (s1 <= -5e29f) ? 0.f : __expf(s1 - mnew);
      float p2 = (s2 <= -5e29f) ? 0.f : __expf(s2 - mnew);
      float p3 = (s3 <= -5e29f) ? 0.f : __expf(s3 - mnew);
      float rsum = p0 + p1 + p2 + p3;
      rsum += __shfl_xor(rsum, 1, 16);
      rsum += __shfl_xor(rsum, 2, 16);
      rsum += __shfl_xor(rsum, 4, 16);
      rsum += __shfl_xor(rsum, 8, 16);
      l_run[i] = l_run[i] * fac + rsum;
      m_run[i] = mnew;
      #pragma unroll
      for (int j = 0; j < 4; ++j) o[i][j] *= fac;
      *(float4*)(&Ps[ty * 4 + i][tx * 4]) = make_float4(p0, p1, p2, p3);
    }
    __syncthreads();

    // O += P @ V
    #pragma unroll 16
    for (int c = 0; c < 64; ++c) {
      float a[4], bb[4];
      #pragma unroll
      for (int i = 0; i < 4; ++i) a[i]  = Ps[ty * 4 + i][c];
      #pragma unroll
      for (int j = 0; j < 4; ++j) bb[j] = Vs[c][tx * 4 + j];
      #pragma unroll
      for (int i = 0; i < 4; ++i)
        #pragma unroll
        for (int j = 0; j < 4; ++j) o[i][j] += a[i] * bb[j];
    }
  }

  float* Op = out + ((long)(b * N + n0)) * D + h * 64;
  #pragma unroll
  for (int i = 0; i < 4; ++i) {
    const float invl = 1.f / l_run[i];   // >=1 unmasked entry (self-loop)
    float4 v = make_float4(o[i][0] * invl, o[i][1] * invl,
                           o[i][2] * invl, o[i][3] * invl);
    *(float4*)(Op + (long)(ty * 4 + i) * D + tx * 4) = v;
  }
}

// ---------------------------------------------------------------------------
// Fused GRU (single step, torch semantics) + LayerNorm. One block per row.
// ---------------------------------------------------------------------------
__global__ __launch_bounds__(256) void gru_ln_kernel(
    const float* __restrict__ gi, const float* __restrict__ gh,
    const float* __restrict__ h, const float* __restrict__ ln_g,
    const float* __restrict__ ln_b, float* __restrict__ out)
{
  const long row = blockIdx.x;
  const int tid = threadIdx.x;
  const float* gir = gi + row * 1536;
  const float* ghr = gh + row * 1536;
  const float* hr  = h  + row * 512;

  float val[2];
  float sum = 0.f, sq = 0.f;
  #pragma unroll
  for (int l = 0; l < 2; ++l) {
    int d = tid + l * 256;
    float r = 1.f / (1.f + __expf(-(gir[d] + ghr[d])));
    float z = 1.f / (1.f + __expf(-(gir[512 + d] + ghr[512 + d])));
    float n = tanhf(gir[1024 + d] + r * ghr[1024 + d]);
    float hv = hr[d];
    float hn = (1.f - z) * n + z * hv;
    val[l] = hn; sum += hn; sq += hn * hn;
  }
  #pragma unroll
  for (int off = 32; off > 0; off >>= 1) {
    sum += __shfl_xor(sum, off);
    sq  += __shfl_xor(sq,  off);
  }
  __shared__ float s1[4], s2[4];
  if ((tid & 63) == 0) { s1[tid >> 6] = sum; s2[tid >> 6] = sq; }
  __syncthreads();
  sum = s1[0] + s1[1] + s1[2] + s1[3];
  sq  = s2[0] + s2[1] + s2[2] + s2[3];
  const float mu  = sum * (1.f / 512.f);
  float var = sq * (1.f / 512.f) - mu * mu;
  var = fmaxf(var, 0.f);
  const float inv = rsqrtf(var + 1e-5f);
  #pragma unroll
  for (int l = 0; l < 2; ++l) {
    int d = tid + l * 256;
    out[row * 512 + d] = (val[l] - mu) * inv * ln_g[d] + ln_b[d];
  }
}

// ---------------------------------------------------------------------------
extern "C" void kernel_launch(void* const* d_in, const int* in_sizes, int n_in,
                              void* d_out, int out_size, void* d_ws, size_t ws_size,
                              hipStream_t stream) {
  (void)in_sizes; (void)n_in; (void)out_size; (void)ws_size;
  const float* inputs   = (const float*)d_in[0];
  const float* memory   = (const float*)d_in[1];
  const int*   graph    = (const int*)  d_in[2];
  const float* w_head_w = (const float*)d_in[3];
  const float* w_head_b = (const float*)d_in[4];
  const float* w_tail_w = (const float*)d_in[5];
  const float* w_tail_b = (const float*)d_in[6];
  const float* w_info_w = (const float*)d_in[7];
  const float* w_info_b = (const float*)d_in[8];
  const float* w_comb_w = (const float*)d_in[9];
  const float* w_comb_b = (const float*)d_in[10];
  const float* gru_w_ih = (const float*)d_in[11];
  const float* gru_w_hh = (const float*)d_in[12];
  const float* gru_b_ih = (const float*)d_in[13];
  const float* gru_b_hh = (const float*)d_in[14];
  const float* ln_g     = (const float*)d_in[15];
  const float* ln_b     = (const float*)d_in[16];
  float* out = (float*)d_out;

  // workspace layout (floats): 128 MiB total
  float* ws   = (float*)d_ws;
  float* head = ws;                  // M*D   = 4,194,304
  float* tail = ws + 4194304;
  float* info = ws + 8388608;
  float* attn = ws + 12582912;       // M*D
  float* hbuf = ws + 16777216;       // M*D (comb output = GRU h)
  float* gh   = ws + 20971520;       // M*3D = 12,582,912
  float* gi   = ws;                  // aliases head/tail/info (dead by then)

  const dim3 blk(256);
  // projections: C = A @ W^T + b
  gemm_bias<<<dim3(8, 64),  blk, 0, stream>>>(inputs, w_head_w, w_head_b, head, D, D);
  gemm_bias<<<dim3(8, 64),  blk, 0, stream>>>(memory, w_tail_w, w_tail_b, tail, D, D);
  gemm_bias<<<dim3(8, 64),  blk, 0, stream>>>(memory, w_info_w, w_info_b, info, D, D);
  // fused masked attention -> [B,N,D] (head-major columns)
  attn_fused<<<dim3(16, 64), blk, 0, stream>>>(head, tail, info, graph, attn);
  // comb projection -> GRU hidden h
  gemm_bias<<<dim3(8, 64),  blk, 0, stream>>>(attn, w_comb_w, w_comb_b, hbuf, D, D);
  // GRU gate GEMMs
  gemm_bias<<<dim3(24, 64), blk, 0, stream>>>(hbuf,   gru_w_hh, gru_b_hh, gh, 1536, D);
  gemm_bias<<<dim3(24, 64), blk, 0, stream>>>(inputs, gru_w_ih, gru_b_ih, gi, 1536, D);
  // fused GRU + LayerNorm
  gru_ln_kernel<<<dim3(8192), blk, 0, stream>>>(gi, gh, hbuf, ln_g, ln_b, out);
}

// Round 4
// 687.346 us; speedup vs baseline: 1.4285x; 1.4285x over previous
//
#include <hip/hip_runtime.h>

#define NEGF (-1e30f)
#define NTOK 8192          // B*N
#define DMODEL 512
#define KDIM 512
#define NB 1024            // N
#define BATCH 8

typedef unsigned short u16;
typedef short bf16x8 __attribute__((ext_vector_type(8)));
typedef float f32x4 __attribute__((ext_vector_type(4)));

__device__ __forceinline__ float b2f(u16 u) {
  union { float f; unsigned int i; } c; c.i = ((unsigned int)u) << 16; return c.f;
}
__device__ __forceinline__ u16 f2b(float f) {   // RN-even
  union { float f; unsigned int i; } c; c.f = f;
  unsigned int r = c.i + 0x7fffu + ((c.i >> 16) & 1u);
  return (u16)(r >> 16);
}

// async global->LDS, 16B/lane; LDS dest is wave-uniform base + lane*16 (linear)
__device__ __forceinline__ void gload_lds16(const void* g, void* l) {
  __builtin_amdgcn_global_load_lds((const __attribute__((address_space(1))) void*)g,
                                   (__attribute__((address_space(3))) void*)l, 16, 0, 0);
}

// ---------------------------------------------------------------------------
// split fp32 -> (hi, lo) bf16 pair.  hi = rn(x), lo = rn(x - hi).
// ---------------------------------------------------------------------------
__global__ __launch_bounds__(256) void split_f32(
    const float* __restrict__ x, u16* __restrict__ hi, u16* __restrict__ lo, int n)
{
  int i = (blockIdx.x * 256 + threadIdx.x) * 4;
  if (i >= n) return;
  float4 v = *(const float4*)(x + i);
  ushort4 h, l;
  h.x = f2b(v.x); l.x = f2b(v.x - b2f(h.x));
  h.y = f2b(v.y); l.y = f2b(v.y - b2f(h.y));
  h.z = f2b(v.z); l.z = f2b(v.z - b2f(h.z));
  h.w = f2b(v.w); l.w = f2b(v.w - b2f(h.w));
  *(ushort4*)(hi + i) = h;
  *(ushort4*)(lo + i) = l;
}

// ---------------------------------------------------------------------------
// Split-bf16 MFMA GEMM:  C[m,n] = sum_k A[m,k]*W[n,k] + bias[n]
// A,W given as bf16 (hi,lo) pairs; fp32 accumulate; error ~2^-18 (bf16x3).
// BM=128 BN=64 BK=32, 256 thr = 4 waves (2x2), wave tile 64x32 = 4x2 16x16 frags.
// Per K-step/wave: 12 ds_read_b128 : 24 MFMA (m97-like 1:2 ratio).
// LDS 24KB single-buffer, 2-barrier loop. Source-side XOR swizzle
// (k-slot ^= row&3) keeps frag ds_read_b128 at 2-way aliasing (= free, m136).
// MODE 0: fp32 out; 1: bf16 out; 2: split (hi,lo) out.
// ---------------------------------------------------------------------------
template<int MODE>
__global__ __launch_bounds__(256) void gemm_mfma(
    const u16* __restrict__ Ahi, const u16* __restrict__ Alo,
    const u16* __restrict__ Whi, const u16* __restrict__ Wlo,
    const float* __restrict__ bias,
    float* __restrict__ outF, u16* __restrict__ outB, u16* __restrict__ outL,
    int Ndim)
{
  __shared__ char smem[24576];  // Ahi 0 | Alo 8K | Bhi 16K | Blo 20K
  const int tid  = threadIdx.x;
  const int wave = tid >> 6, lane = tid & 63;
  const int wr = wave >> 1, wc = wave & 1;
  const int lrow = lane & 15, kg = lane >> 4;
  const int row0 = blockIdx.y * 128, col0 = blockIdx.x * 64;

  // staging slot geometry (16B slots; A tile 512 slots = 2 issues, B 256 = 1)
  const int sA0 = tid, sA1 = 256 + tid;
  const int rA0 = sA0 >> 2, rA1 = sA1 >> 2;
  const int cA0 = ((sA0 & 3) ^ (rA0 & 3)) * 8;   // swizzled k-element offset
  const int cA1 = ((sA1 & 3) ^ (rA1 & 3)) * 8;
  const int rB  = tid >> 2;
  const int cB  = ((tid & 3) ^ (rB & 3)) * 8;

  const long arow0 = (long)row0 * KDIM;
  const long brow0 = (long)col0 * KDIM;

  f32x4 acc[4][2];
  #pragma unroll
  for (int m = 0; m < 4; ++m)
    #pragma unroll
    for (int n = 0; n < 2; ++n) acc[m][n] = (f32x4){0.f, 0.f, 0.f, 0.f};

  const int swz = ((kg ^ (lrow & 3)) << 4);  // byte offset of k-group within row

  for (int k0 = 0; k0 < KDIM; k0 += 32) {
    gload_lds16(Ahi + arow0 + (long)rA0 * KDIM + k0 + cA0, smem + sA0 * 16);
    gload_lds16(Ahi + arow0 + (long)rA1 * KDIM + k0 + cA1, smem + sA1 * 16);
    gload_lds16(Alo + arow0 + (long)rA0 * KDIM + k0 + cA0, smem + 8192 + sA0 * 16);
    gload_lds16(Alo + arow0 + (long)rA1 * KDIM + k0 + cA1, smem + 8192 + sA1 * 16);
    gload_lds16(Whi + brow0 + (long)rB * KDIM + k0 + cB, smem + 16384 + tid * 16);
    gload_lds16(Wlo + brow0 + (long)rB * KDIM + k0 + cB, smem + 20480 + tid * 16);
    __syncthreads();   // compiler drains vmcnt(0) before s_barrier

    bf16x8 ah[4], al[4], bh[2], bl[2];
    #pragma unroll
    for (int m = 0; m < 4; ++m) {
      const int r = wr * 64 + m * 16 + lrow;           // r&3 == lrow&3
      ah[m] = *(const bf16x8*)(smem + r * 64 + swz);
      al[m] = *(const bf16x8*)(smem + 8192 + r * 64 + swz);
    }
    #pragma unroll
    for (int n = 0; n < 2; ++n) {
      const int r = wc * 32 + n * 16 + lrow;
      bh[n] = *(const bf16x8*)(smem + 16384 + r * 64 + swz);
      bl[n] = *(const bf16x8*)(smem + 20480 + r * 64 + swz);
    }
    #pragma unroll
    for (int m = 0; m < 4; ++m)
      #pragma unroll
      for (int n = 0; n < 2; ++n) {
        acc[m][n] = __builtin_amdgcn_mfma_f32_16x16x32_bf16(ah[m], bh[n], acc[m][n], 0, 0, 0);
        acc[m][n] = __builtin_amdgcn_mfma_f32_16x16x32_bf16(ah[m], bl[n], acc[m][n], 0, 0, 0);
        acc[m][n] = __builtin_amdgcn_mfma_f32_16x16x32_bf16(al[m], bh[n], acc[m][n], 0, 0, 0);
      }
    __syncthreads();
  }

  // epilogue: C/D map col=lane&15, row=(lane>>4)*4+q  [m89-verified]
  #pragma unroll
  for (int m = 0; m < 4; ++m) {
    const int grow = row0 + wr * 64 + m * 16 + kg * 4;
    #pragma unroll
    for (int n = 0; n < 2; ++n) {
      const int gcol = col0 + wc * 32 + n * 16 + lrow;
      const float bv = bias[gcol];
      #pragma unroll
      for (int q = 0; q < 4; ++q) {
        const float v = acc[m][n][q] + bv;
        const long idx = (long)(grow + q) * Ndim + gcol;
        if constexpr (MODE == 0) {
          outF[idx] = v;
        } else if constexpr (MODE == 1) {
          outB[idx] = f2b(v);
        } else {
          const u16 hb = f2b(v);
          outB[idx] = hb;
          outL[idx] = f2b(v - b2f(hb));
        }
      }
    }
  }
}

// ---------------------------------------------------------------------------
// Fused masked attention (fp32 math, unchanged this round).
// Epilogue now emits (hi,lo) bf16 for the split comb GEMM.
// ---------------------------------------------------------------------------
__global__ __launch_bounds__(256) void attn_fused(
    const float* __restrict__ head, const float* __restrict__ tail,
    const float* __restrict__ info, const int* __restrict__ graph,
    u16* __restrict__ ohi, u16* __restrict__ olo)
{
  const int bh = blockIdx.y;
  const int b  = bh >> 3;
  const int h  = bh & 7;
  const int n0 = blockIdx.x * 64;
  const int tid = threadIdx.x;
  const int ty = tid >> 4;
  const int tx = tid & 15;
  const int rr = tid >> 4;
  const int dr = (tid & 15) * 4;

  __shared__ float Hs[64][68];
  __shared__ float Ts[64][68];
  __shared__ float Vs[64][68];
  __shared__ float Ps[64][68];

  const float* Hp = head + ((long)(b * NB + n0)) * DMODEL + h * 64;
  const float* Tp = tail + ((long)b * NB) * DMODEL + h * 64;
  const float* Vp = info + ((long)b * NB) * DMODEL + h * 64;

  #pragma unroll
  for (int q = 0; q < 4; ++q) {
    int r = rr + q * 16;
    float4 v = *(const float4*)(Hp + (long)r * DMODEL + dr);
    Hs[dr + 0][r] = v.x; Hs[dr + 1][r] = v.y;
    Hs[dr + 2][r] = v.z; Hs[dr + 3][r] = v.w;
  }

  float o[4][4];
  #pragma unroll
  for (int i = 0; i < 4; ++i)
    #pragma unroll
    for (int j = 0; j < 4; ++j) o[i][j] = 0.f;
  float m_run[4], l_run[4];
  #pragma unroll
  for (int i = 0; i < 4; ++i) { m_run[i] = NEGF; l_run[i] = 0.f; }

  const float inv_scale = 0.04419417382415922f;  // 1/sqrt(512)

  for (int t = 0; t < 16; ++t) {
    const int m0 = t * 64;
    __syncthreads();
    #pragma unroll
    for (int q = 0; q < 4; ++q) {
      int c = rr + q * 16;
      float4 v = *(const float4*)(Tp + (long)(m0 + c) * DMODEL + dr);
      Ts[dr + 0][c] = v.x; Ts[dr + 1][c] = v.y;
      Ts[dr + 2][c] = v.z; Ts[dr + 3][c] = v.w;
      float4 w = *(const float4*)(Vp + (long)(m0 + c) * DMODEL + dr);
      *(float4*)(&Vs[c][dr]) = w;
    }
    __syncthreads();

    float s[4][4];
    #pragma unroll
    for (int i = 0; i < 4; ++i)
      #pragma unroll
      for (int j = 0; j < 4; ++j) s[i][j] = 0.f;
    #pragma unroll 16
    for (int d = 0; d < 64; ++d) {
      float a[4], bb[4];
      #pragma unroll
      for (int i = 0; i < 4; ++i) a[i]  = Hs[d][ty * 4 + i];
      #pragma unroll
      for (int j = 0; j < 4; ++j) bb[j] = Ts[d][tx * 4 + j];
      #pragma unroll
      for (int i = 0; i < 4; ++i)
        #pragma unroll
        for (int j = 0; j < 4; ++j) s[i][j] += a[i] * bb[j];
    }

    #pragma unroll
    for (int i = 0; i < 4; ++i) {
      const int4 g = *(const int4*)(graph +
          ((long)b * NB + (n0 + ty * 4 + i)) * NB + m0 + tx * 4);
      float s0 = g.x ? s[i][0] * inv_scale : NEGF;
      float s1 = g.y ? s[i][1] * inv_scale : NEGF;
      float s2 = g.z ? s[i][2] * inv_scale : NEGF;
      float s3 = g.w ? s[i][3] * inv_scale : NEGF;
      float rmax = fmaxf(fmaxf(s0, s1), fmaxf(s2, s3));
      rmax = fmaxf(rmax, __shfl_xor(rmax, 1, 16));
      rmax = fmaxf(rmax, __shfl_xor(rmax, 2, 16));
      rmax = fmaxf(rmax, __shfl_xor(rmax, 4, 16));
      rmax = fmaxf(rmax, __shfl_xor(rmax, 8, 16));
      const float mnew = fmaxf(m_run[i], rmax);
      const float fac  = __expf(m_run[i] - mnew);
      float p0 = (s0 <= -5e29f) ? 0.f : __expf(s0 - mnew);
      float p1 = (s1 <= -5e29f) ? 0.f : __expf(s1 - mnew);
      float p2 = (s2 <= -5e29f) ? 0.f : __expf(s2 - mnew);
      float p3 = (s3 <= -5e29f) ? 0.f : __expf(s3 - mnew);
      float rsum = p0 + p1 + p2 + p3;
      rsum += __shfl_xor(rsum, 1, 16);
      rsum += __shfl_xor(rsum, 2, 16);
      rsum += __shfl_xor(rsum, 4, 16);
      rsum += __shfl_xor(rsum, 8, 16);
      l_run[i] = l_run[i] * fac + rsum;
      m_run[i] = mnew;
      #pragma unroll
      for (int j = 0; j < 4; ++j) o[i][j] *= fac;
      *(float4*)(&Ps[ty * 4 + i][tx * 4]) = make_float4(p0, p1, p2, p3);
    }
    __syncthreads();

    #pragma unroll 16
    for (int c = 0; c < 64; ++c) {
      float a[4], bb[4];
      #pragma unroll
      for (int i = 0; i < 4; ++i) a[i]  = Ps[ty * 4 + i][c];
      #pragma unroll
      for (int j = 0; j < 4; ++j) bb[j] = Vs[c][tx * 4 + j];
      #pragma unroll
      for (int i = 0; i < 4; ++i)
        #pragma unroll
        for (int j = 0; j < 4; ++j) o[i][j] += a[i] * bb[j];
    }
  }

  const long obase = ((long)(b * NB + n0)) * DMODEL + h * 64;
  #pragma unroll
  for (int i = 0; i < 4; ++i) {
    const float invl = 1.f / l_run[i];
    const long idx = obase + (long)(ty * 4 + i) * DMODEL + tx * 4;
    #pragma unroll
    for (int j = 0; j < 4; ++j) {
      const float v = o[i][j] * invl;
      const u16 hb = f2b(v);
      ohi[idx + j] = hb;
      olo[idx + j] = f2b(v - b2f(hb));
    }
  }
}

// ---------------------------------------------------------------------------
// Fused GRU + LayerNorm. gi fp32, gh bf16, h = hbuf_hi + hbuf_lo (fp32-exact).
// ---------------------------------------------------------------------------
__global__ __launch_bounds__(256) void gru_ln_kernel(
    const float* __restrict__ gi, const u16* __restrict__ gh,
    const u16* __restrict__ hhi, const u16* __restrict__ hlo,
    const float* __restrict__ ln_g, const float* __restrict__ ln_b,
    float* __restrict__ out)
{
  const long row = blockIdx.x;
  const int tid = threadIdx.x;
  const float* gir = gi + row * 1536;
  const u16*   ghr = gh + row * 1536;

  float val[2];
  float sum = 0.f, sq = 0.f;
  #pragma unroll
  for (int l = 0; l < 2; ++l) {
    int d = tid + l * 256;
    float r = 1.f / (1.f + __expf(-(gir[d] + b2f(ghr[d]))));
    float z = 1.f / (1.f + __expf(-(gir[512 + d] + b2f(ghr[512 + d]))));
    float n = tanhf(gir[1024 + d] + r * b2f(ghr[1024 + d]));
    float hv = b2f(hhi[row * 512 + d]) + b2f(hlo[row * 512 + d]);
    float hn = (1.f - z) * n + z * hv;
    val[l] = hn; sum += hn; sq += hn * hn;
  }
  #pragma unroll
  for (int off = 32; off > 0; off >>= 1) {
    sum += __shfl_xor(sum, off);
    sq  += __shfl_xor(sq,  off);
  }
  __shared__ float s1[4], s2[4];
  if ((tid & 63) == 0) { s1[tid >> 6] = sum; s2[tid >> 6] = sq; }
  __syncthreads();
  sum = s1[0] + s1[1] + s1[2] + s1[3];
  sq  = s2[0] + s2[1] + s2[2] + s2[3];
  const float mu  = sum * (1.f / 512.f);
  float var = sq * (1.f / 512.f) - mu * mu;
  var = fmaxf(var, 0.f);
  const float inv = rsqrtf(var + 1e-5f);
  #pragma unroll
  for (int l = 0; l < 2; ++l) {
    int d = tid + l * 256;
    out[row * 512 + d] = (val[l] - mu) * inv * ln_g[d] + ln_b[d];
  }
}

// ---------------------------------------------------------------------------
extern "C" void kernel_launch(void* const* d_in, const int* in_sizes, int n_in,
                              void* d_out, int out_size, void* d_ws, size_t ws_size,
                              hipStream_t stream) {
  (void)in_sizes; (void)n_in; (void)out_size; (void)ws_size;
  const float* inputs   = (const float*)d_in[0];
  const float* memory   = (const float*)d_in[1];
  const int*   graph    = (const int*)  d_in[2];
  const float* w_head_w = (const float*)d_in[3];
  const float* w_head_b = (const float*)d_in[4];
  const float* w_tail_w = (const float*)d_in[5];
  const float* w_tail_b = (const float*)d_in[6];
  const float* w_info_w = (const float*)d_in[7];
  const float* w_info_b = (const float*)d_in[8];
  const float* w_comb_w = (const float*)d_in[9];
  const float* w_comb_b = (const float*)d_in[10];
  const float* gru_w_ih = (const float*)d_in[11];
  const float* gru_w_hh = (const float*)d_in[12];
  const float* gru_b_ih = (const float*)d_in[13];
  const float* gru_b_hh = (const float*)d_in[14];
  const float* ln_g     = (const float*)d_in[15];
  const float* ln_b     = (const float*)d_in[16];
  float* out = (float*)d_out;

  // ---- workspace (byte offsets; 128 MiB total, aliased by liveness) ----
  char* W = (char*)d_ws;
  const size_t MB = 1u << 20;
  u16* in_hi  = (u16*)(W + 0 * MB);      // live: head GEMM, gi GEMM
  u16* in_lo  = (u16*)(W + 8 * MB);
  u16* mem_hi = (u16*)(W + 16 * MB);     // live: tail/info GEMMs
  u16* mem_lo = (u16*)(W + 24 * MB);
  u16* hb_hi  = mem_hi;                  // reuse: comb out -> gh GEMM, gru_ln
  u16* hb_lo  = mem_lo;
  u16* wh_hi  = (u16*)(W + 32 * MB);     // weights: 8x256K + 4x768K elems
  u16* wh_lo  = wh_hi + 262144;
  u16* wt_hi  = wh_lo + 262144;
  u16* wt_lo  = wt_hi + 262144;
  u16* wi_hi  = wt_lo + 262144;
  u16* wi_lo  = wi_hi + 262144;
  u16* wc_hi  = wi_lo + 262144;
  u16* wc_lo  = wc_hi + 262144;
  u16* wih_hi = wc_lo + 262144;
  u16* wih_lo = wih_hi + 786432;
  u16* whh_hi = wih_lo + 786432;
  u16* whh_lo = whh_hi + 786432;
  float* head = (float*)(W + 48 * MB);   // live until attn
  float* tail = head + 4194304;
  float* info = tail + 4194304;
  float* giF  = (float*)(W + 48 * MB);   // fp32 [8192][1536] = 48MB, reuses head/tail/info
  u16* attn_hi = (u16*)(W + 96 * MB);    // live: attn -> comb
  u16* attn_lo = (u16*)(W + 104 * MB);
  u16* ghB     = (u16*)(W + 104 * MB);   // bf16 [8192][1536] = 24MB (104..128MB),
                                         // clobbers attn_lo AFTER comb consumed it

  const dim3 blk(256);
  const int nTok = NTOK * DMODEL;        // 4,194,304

  // splits: activations + weights -> (hi, lo) bf16
  split_f32<<<dim3(nTok / 1024), blk, 0, stream>>>(inputs, in_hi, in_lo, nTok);
  split_f32<<<dim3(nTok / 1024), blk, 0, stream>>>(memory, mem_hi, mem_lo, nTok);
  split_f32<<<dim3(256), blk, 0, stream>>>(w_head_w, wh_hi, wh_lo, 262144);
  split_f32<<<dim3(256), blk, 0, stream>>>(w_tail_w, wt_hi, wt_lo, 262144);
  split_f32<<<dim3(256), blk, 0, stream>>>(w_info_w, wi_hi, wi_lo, 262144);
  split_f32<<<dim3(256), blk, 0, stream>>>(w_comb_w, wc_hi, wc_lo, 262144);
  split_f32<<<dim3(768), blk, 0, stream>>>(gru_w_ih, wih_hi, wih_lo, 786432);
  split_f32<<<dim3(768), blk, 0, stream>>>(gru_w_hh, whh_hi, whh_lo, 786432);

  // projections (fp32 out for fp32 attention)
  gemm_mfma<0><<<dim3(8, 64), blk, 0, stream>>>(in_hi,  in_lo,  wh_hi, wh_lo, w_head_b, head, nullptr, nullptr, 512);
  gemm_mfma<0><<<dim3(8, 64), blk, 0, stream>>>(mem_hi, mem_lo, wt_hi, wt_lo, w_tail_b, tail, nullptr, nullptr, 512);
  gemm_mfma<0><<<dim3(8, 64), blk, 0, stream>>>(mem_hi, mem_lo, wi_hi, wi_lo, w_info_b, info, nullptr, nullptr, 512);

  // attention (fp32 math) -> split bf16 output
  attn_fused<<<dim3(16, 64), blk, 0, stream>>>(head, tail, info, graph, attn_hi, attn_lo);

  // comb -> hbuf (split out; h reconstructed as hi+lo later)
  gemm_mfma<2><<<dim3(8, 64), blk, 0, stream>>>(attn_hi, attn_lo, wc_hi, wc_lo, w_comb_b, nullptr, hb_hi, hb_lo, 512);

  // GRU gate GEMMs: gh bf16 out, gi fp32 out
  gemm_mfma<1><<<dim3(24, 64), blk, 0, stream>>>(hb_hi, hb_lo, whh_hi, whh_lo, gru_b_hh, nullptr, ghB, nullptr, 1536);
  gemm_mfma<0><<<dim3(24, 64), blk, 0, stream>>>(in_hi, in_lo, wih_hi, wih_lo, gru_b_ih, giF, nullptr, nullptr, 1536);

  // fused GRU + LayerNorm
  gru_ln_kernel<<<dim3(8192), blk, 0, stream>>>(giF, ghB, hb_hi, hb_lo, ln_g, ln_b, out);
}

// Round 5
// 442.648 us; speedup vs baseline: 2.2181x; 1.5528x over previous
//
#include <hip/hip_runtime.h>

#define NEGF (-1e30f)
#define NTOK 8192          // B*N
#define DMODEL 512
#define KDIM 512
#define NB 1024            // N
#define BATCH 8

typedef unsigned short u16;
typedef short bf16x8 __attribute__((ext_vector_type(8)));
typedef float f32x4 __attribute__((ext_vector_type(4)));

__device__ __forceinline__ float b2f(u16 u) {
  union { float f; unsigned int i; } c; c.i = ((unsigned int)u) << 16; return c.f;
}
__device__ __forceinline__ u16 f2b(float f) {   // RN-even
  union { float f; unsigned int i; } c; c.f = f;
  unsigned int r = c.i + 0x7fffu + ((c.i >> 16) & 1u);
  return (u16)(r >> 16);
}

// async global->LDS, 16B/lane; LDS dest is wave-uniform base + lane*16 (linear)
__device__ __forceinline__ void gload_lds16(const void* g, void* l) {
  __builtin_amdgcn_global_load_lds((const __attribute__((address_space(1))) void*)g,
                                   (__attribute__((address_space(3))) void*)l, 16, 0, 0);
}

// ---------------------------------------------------------------------------
// split fp32 -> (hi, lo) bf16 pair.  hi = rn(x), lo = rn(x - hi).
// ---------------------------------------------------------------------------
__global__ __launch_bounds__(256) void split_f32(
    const float* __restrict__ x, u16* __restrict__ hi, u16* __restrict__ lo, int n)
{
  int i = (blockIdx.x * 256 + threadIdx.x) * 4;
  if (i >= n) return;
  float4 v = *(const float4*)(x + i);
  ushort4 h, l;
  h.x = f2b(v.x); l.x = f2b(v.x - b2f(h.x));
  h.y = f2b(v.y); l.y = f2b(v.y - b2f(h.y));
  h.z = f2b(v.z); l.z = f2b(v.z - b2f(h.z));
  h.w = f2b(v.w); l.w = f2b(v.w - b2f(h.w));
  *(ushort4*)(hi + i) = h;
  *(ushort4*)(lo + i) = l;
}

// ---------------------------------------------------------------------------
// pack graph (int32 0/1, [B][N][N]) -> bitmask [B][N][N/32]  (32MB -> 1MB)
// word w covers cols w*32..w*32+31 of its row; bit j = col w*32+j.
// ---------------------------------------------------------------------------
__global__ __launch_bounds__(256) void pack_graph(
    const int* __restrict__ g, unsigned* __restrict__ bits)
{
  const long w = (long)blockIdx.x * 256 + threadIdx.x;   // 262144 words
  const int* p = g + w * 32;
  unsigned m = 0;
  #pragma unroll
  for (int j = 0; j < 8; ++j) {
    int4 v = *(const int4*)(p + j * 4);
    m |= (v.x != 0 ? 1u : 0u) << (j * 4 + 0);
    m |= (v.y != 0 ? 1u : 0u) << (j * 4 + 1);
    m |= (v.z != 0 ? 1u : 0u) << (j * 4 + 2);
    m |= (v.w != 0 ? 1u : 0u) << (j * 4 + 3);
  }
  bits[w] = m;
}

// ---------------------------------------------------------------------------
// Split-bf16 MFMA GEMM:  C[m,n] = sum_k A[m,k]*W[n,k] + bias[n]
// MODE 0: fp32 out; 1: bf16 out (scaled); 2: split (hi,lo) out;
// MODE 3: transposed bf16 out into Vt[b*8+h][d][tok]  (for attention PV).
// ---------------------------------------------------------------------------
template<int MODE>
__global__ __launch_bounds__(256) void gemm_mfma(
    const u16* __restrict__ Ahi, const u16* __restrict__ Alo,
    const u16* __restrict__ Whi, const u16* __restrict__ Wlo,
    const float* __restrict__ bias,
    float* __restrict__ outF, u16* __restrict__ outB, u16* __restrict__ outL,
    float scale, int Ndim)
{
  __shared__ char smem[24576];  // Ahi 0 | Alo 8K | Bhi 16K | Blo 20K
  const int tid  = threadIdx.x;
  const int wave = tid >> 6, lane = tid & 63;
  const int wr = wave >> 1, wc = wave & 1;
  const int lrow = lane & 15, kg = lane >> 4;
  const int row0 = blockIdx.y * 128, col0 = blockIdx.x * 64;

  const int sA0 = tid, sA1 = 256 + tid;
  const int rA0 = sA0 >> 2, rA1 = sA1 >> 2;
  const int cA0 = ((sA0 & 3) ^ (rA0 & 3)) * 8;
  const int cA1 = ((sA1 & 3) ^ (rA1 & 3)) * 8;
  const int rB  = tid >> 2;
  const int cB  = ((tid & 3) ^ (rB & 3)) * 8;

  const long arow0 = (long)row0 * KDIM;
  const long brow0 = (long)col0 * KDIM;

  f32x4 acc[4][2];
  #pragma unroll
  for (int m = 0; m < 4; ++m)
    #pragma unroll
    for (int n = 0; n < 2; ++n) acc[m][n] = (f32x4){0.f, 0.f, 0.f, 0.f};

  const int swz = ((kg ^ (lrow & 3)) << 4);

  for (int k0 = 0; k0 < KDIM; k0 += 32) {
    gload_lds16(Ahi + arow0 + (long)rA0 * KDIM + k0 + cA0, smem + sA0 * 16);
    gload_lds16(Ahi + arow0 + (long)rA1 * KDIM + k0 + cA1, smem + sA1 * 16);
    gload_lds16(Alo + arow0 + (long)rA0 * KDIM + k0 + cA0, smem + 8192 + sA0 * 16);
    gload_lds16(Alo + arow0 + (long)rA1 * KDIM + k0 + cA1, smem + 8192 + sA1 * 16);
    gload_lds16(Whi + brow0 + (long)rB * KDIM + k0 + cB, smem + 16384 + tid * 16);
    gload_lds16(Wlo + brow0 + (long)rB * KDIM + k0 + cB, smem + 20480 + tid * 16);
    __syncthreads();

    bf16x8 ah[4], al[4], bh[2], bl[2];
    #pragma unroll
    for (int m = 0; m < 4; ++m) {
      const int r = wr * 64 + m * 16 + lrow;
      ah[m] = *(const bf16x8*)(smem + r * 64 + swz);
      al[m] = *(const bf16x8*)(smem + 8192 + r * 64 + swz);
    }
    #pragma unroll
    for (int n = 0; n < 2; ++n) {
      const int r = wc * 32 + n * 16 + lrow;
      bh[n] = *(const bf16x8*)(smem + 16384 + r * 64 + swz);
      bl[n] = *(const bf16x8*)(smem + 20480 + r * 64 + swz);
    }
    #pragma unroll
    for (int m = 0; m < 4; ++m)
      #pragma unroll
      for (int n = 0; n < 2; ++n) {
        acc[m][n] = __builtin_amdgcn_mfma_f32_16x16x32_bf16(ah[m], bh[n], acc[m][n], 0, 0, 0);
        acc[m][n] = __builtin_amdgcn_mfma_f32_16x16x32_bf16(ah[m], bl[n], acc[m][n], 0, 0, 0);
        acc[m][n] = __builtin_amdgcn_mfma_f32_16x16x32_bf16(al[m], bh[n], acc[m][n], 0, 0, 0);
      }
    __syncthreads();
  }

  // epilogue: C/D map col=lane&15, row=(lane>>4)*4+q
  #pragma unroll
  for (int m = 0; m < 4; ++m) {
    const int grow = row0 + wr * 64 + m * 16 + kg * 4;
    #pragma unroll
    for (int n = 0; n < 2; ++n) {
      const int gcol = col0 + wc * 32 + n * 16 + lrow;
      const float bv = bias[gcol];
      #pragma unroll
      for (int q = 0; q < 4; ++q) {
        const float v = acc[m][n][q] + bv;
        if constexpr (MODE == 0) {
          outF[(long)(grow + q) * Ndim + gcol] = v;
        } else if constexpr (MODE == 1) {
          outB[(long)(grow + q) * Ndim + gcol] = f2b(v * scale);
        } else if constexpr (MODE == 2) {
          const u16 hb = f2b(v);
          outB[(long)(grow + q) * Ndim + gcol] = hb;
          outL[(long)(grow + q) * Ndim + gcol] = f2b(v - b2f(hb));
        } else {  // MODE 3: Vt[(b*8+h)][d][tok]
          const int tok = (grow + q) & 1023;
          const int bb  = (grow + q) >> 10;
          const int hh  = gcol >> 6;
          const int dd  = gcol & 63;
          outB[(((long)(bb * 8 + hh)) * 64 + dd) * 1024 + tok] = f2b(v);
        }
      }
    }
  }
}

// ---------------------------------------------------------------------------
// MFMA flash attention. Block = 128 q-rows of one (b,h); 4 waves x 32 rows.
// Q bf16 regs (scale pre-folded), K/Vt staged in LDS (XOR-swizzled via
// pre-swizzled global source), mask from packed bits, fp32 online softmax,
// P through per-wave LDS (no cross-wave barrier), split hi/lo output.
// ---------------------------------------------------------------------------
__global__ __launch_bounds__(256) void attn_mfma(
    const u16* __restrict__ Qb, const u16* __restrict__ Kb,
    const u16* __restrict__ Vt, const unsigned* __restrict__ bits,
    u16* __restrict__ ohi, u16* __restrict__ olo)
{
  const int bh = blockIdx.y;
  const int b  = bh >> 3, h = bh & 7;
  const int n0 = blockIdx.x * 128;
  const int tid = threadIdx.x, wid = tid >> 6, lane = tid & 63;
  const int lx = lane & 15, kg = lane >> 4;

  __shared__ char lds[32768];            // K 8K | Vt 8K | P 16K (4K/wave)
  char* Kl = lds;
  char* Vl = lds + 8192;
  char* Pl = lds + 16384 + wid * 4096;

  // Q frags: A-layout, rows n0+wid*32+m*16+lx, k-octet kg within 32-step
  bf16x8 qf[2][2];
  #pragma unroll
  for (int m = 0; m < 2; ++m)
    #pragma unroll
    for (int ks = 0; ks < 2; ++ks)
      qf[m][ks] = *(const bf16x8*)(Qb +
          (long)(b * NB + n0 + wid * 32 + m * 16 + lx) * DMODEL +
          h * 64 + ks * 32 + kg * 8);

  f32x4 o[2][4];
  float mrun[2][4], lrun[2][4];
  #pragma unroll
  for (int m = 0; m < 2; ++m)
    #pragma unroll
    for (int n = 0; n < 4; ++n) o[m][n] = (f32x4){0.f, 0.f, 0.f, 0.f};
  #pragma unroll
  for (int m = 0; m < 2; ++m)
    #pragma unroll
    for (int q = 0; q < 4; ++q) { mrun[m][q] = -3.0e4f; lrun[m][q] = 0.f; }

  // staging geometry: 512 slots of 16B per 64x64 bf16 tile, 2 issues
  const int s0 = tid, s1 = 256 + tid;
  const int r0 = s0 >> 3, c0 = (s0 & 7) ^ (r0 & 7);
  const int r1 = s1 >> 3, c1 = (s1 & 7) ^ (r1 & 7);
  const u16* Kg = Kb + (long)(b * NB) * DMODEL + h * 64;  // row stride 512
  const u16* Vg = Vt + (long)bh * 64 * 1024;              // d-row stride 1024

  for (int t = 0; t < 16; ++t) {
    const int m0 = t * 64;
    __syncthreads();
    gload_lds16(Kg + (long)(m0 + r0) * DMODEL + c0 * 8, Kl + s0 * 16);
    gload_lds16(Kg + (long)(m0 + r1) * DMODEL + c1 * 8, Kl + s1 * 16);
    gload_lds16(Vg + (long)r0 * 1024 + m0 + c0 * 8, Vl + s0 * 16);
    gload_lds16(Vg + (long)r1 * 1024 + m0 + c1 * 8, Vl + s1 * 16);
    __syncthreads();

    // ---- S = Q K^T (scale folded into Q) ----
    bf16x8 kf[4][2];
    #pragma unroll
    for (int n = 0; n < 4; ++n)
      #pragma unroll
      for (int ks = 0; ks < 2; ++ks) {
        const int col = n * 16 + lx;
        const int slot = ks * 4 + kg;
        kf[n][ks] = *(const bf16x8*)(Kl + col * 128 + ((slot ^ (col & 7)) << 4));
      }
    f32x4 s[2][4];
    #pragma unroll
    for (int m = 0; m < 2; ++m)
      #pragma unroll
      for (int n = 0; n < 4; ++n) {
        s[m][n] = (f32x4){0.f, 0.f, 0.f, 0.f};
        s[m][n] = __builtin_amdgcn_mfma_f32_16x16x32_bf16(qf[m][0], kf[n][0], s[m][n], 0, 0, 0);
        s[m][n] = __builtin_amdgcn_mfma_f32_16x16x32_bf16(qf[m][1], kf[n][1], s[m][n], 0, 0, 0);
      }

    // ---- mask + online softmax (rows live on 16-lane groups, kg fixed) ----
    u16 pb[2][4][4];
    #pragma unroll
    for (int m = 0; m < 2; ++m) {
      const unsigned* bp = bits +
          ((long)(b * NB + n0 + wid * 32 + m * 16 + kg * 4)) * 32 + (m0 >> 5);
      #pragma unroll
      for (int q = 0; q < 4; ++q) {
        const uint2 w = *(const uint2*)(bp + q * 32);
        float sv[4];
        #pragma unroll
        for (int n = 0; n < 4; ++n) {
          const unsigned wd = (n & 2) ? w.y : w.x;
          const int sh = (n & 1) * 16 + lx;
          sv[n] = ((wd >> sh) & 1u) ? s[m][n][q] : NEGF;
        }
        float rmax = fmaxf(fmaxf(sv[0], sv[1]), fmaxf(sv[2], sv[3]));
        rmax = fmaxf(rmax, __shfl_xor(rmax, 1));
        rmax = fmaxf(rmax, __shfl_xor(rmax, 2));
        rmax = fmaxf(rmax, __shfl_xor(rmax, 4));
        rmax = fmaxf(rmax, __shfl_xor(rmax, 8));
        const float mnew = fmaxf(mrun[m][q], rmax);
        const float fac  = __expf(mrun[m][q] - mnew);
        float ps[4], rsum = 0.f;
        #pragma unroll
        for (int n = 0; n < 4; ++n) { ps[n] = __expf(sv[n] - mnew); rsum += ps[n]; }
        rsum += __shfl_xor(rsum, 1);
        rsum += __shfl_xor(rsum, 2);
        rsum += __shfl_xor(rsum, 4);
        rsum += __shfl_xor(rsum, 8);
        lrun[m][q] = lrun[m][q] * fac + rsum;
        mrun[m][q] = mnew;
        #pragma unroll
        for (int n = 0; n < 4; ++n) o[m][n][q] *= fac;
        #pragma unroll
        for (int n = 0; n < 4; ++n) pb[m][n][q] = f2b(ps[n]);
      }
    }

    // ---- P: C-layout -> LDS (per-wave, XOR-swizzled) -> A-layout ----
    #pragma unroll
    for (int m = 0; m < 2; ++m)
      #pragma unroll
      for (int n = 0; n < 4; ++n)
        #pragma unroll
        for (int q = 0; q < 4; ++q) {
          const int row = m * 16 + kg * 4 + q;
          *(u16*)(Pl + row * 128 + ((n * 32 + lx * 2) ^ ((row & 7) << 4))) =
              pb[m][n][q];
        }
    bf16x8 pf[2][2], vf[4][2];
    #pragma unroll
    for (int m = 0; m < 2; ++m)
      #pragma unroll
      for (int ks = 0; ks < 2; ++ks) {
        const int row = m * 16 + lx;
        const int slot = ks * 4 + kg;
        pf[m][ks] = *(const bf16x8*)(Pl + row * 128 + ((slot ^ (row & 7)) << 4));
      }
    #pragma unroll
    for (int n = 0; n < 4; ++n)
      #pragma unroll
      for (int ks = 0; ks < 2; ++ks) {
        const int col = n * 16 + lx;
        const int slot = ks * 4 + kg;
        vf[n][ks] = *(const bf16x8*)(Vl + col * 128 + ((slot ^ (col & 7)) << 4));
      }
    #pragma unroll
    for (int m = 0; m < 2; ++m)
      #pragma unroll
      for (int n = 0; n < 4; ++n) {
        o[m][n] = __builtin_amdgcn_mfma_f32_16x16x32_bf16(pf[m][0], vf[n][0], o[m][n], 0, 0, 0);
        o[m][n] = __builtin_amdgcn_mfma_f32_16x16x32_bf16(pf[m][1], vf[n][1], o[m][n], 0, 0, 0);
      }
  }

  // ---- epilogue: O/l, split hi/lo, [tok][h*64+d] layout ----
  #pragma unroll
  for (int m = 0; m < 2; ++m)
    #pragma unroll
    for (int q = 0; q < 4; ++q) {
      const float inv = 1.f / lrun[m][q];
      const long rowg = (long)(b * NB + n0 + wid * 32 + m * 16 + kg * 4 + q);
      #pragma unroll
      for (int n = 0; n < 4; ++n) {
        const long idx = rowg * DMODEL + h * 64 + n * 16 + lx;
        const float v = o[m][n][q] * inv;
        const u16 hb = f2b(v);
        ohi[idx] = hb;
        olo[idx] = f2b(v - b2f(hb));
      }
    }
}

// ---------------------------------------------------------------------------
// Fused GRU + LayerNorm. gi fp32, gh bf16, h = hbuf_hi + hbuf_lo.
// ---------------------------------------------------------------------------
__global__ __launch_bounds__(256) void gru_ln_kernel(
    const float* __restrict__ gi, const u16* __restrict__ gh,
    const u16* __restrict__ hhi, const u16* __restrict__ hlo,
    const float* __restrict__ ln_g, const float* __restrict__ ln_b,
    float* __restrict__ out)
{
  const long row = blockIdx.x;
  const int tid = threadIdx.x;
  const float* gir = gi + row * 1536;
  const u16*   ghr = gh + row * 1536;

  float val[2];
  float sum = 0.f, sq = 0.f;
  #pragma unroll
  for (int l = 0; l < 2; ++l) {
    int d = tid + l * 256;
    float r = 1.f / (1.f + __expf(-(gir[d] + b2f(ghr[d]))));
    float z = 1.f / (1.f + __expf(-(gir[512 + d] + b2f(ghr[512 + d]))));
    float n = tanhf(gir[1024 + d] + r * b2f(ghr[1024 + d]));
    float hv = b2f(hhi[row * 512 + d]) + b2f(hlo[row * 512 + d]);
    float hn = (1.f - z) * n + z * hv;
    val[l] = hn; sum += hn; sq += hn * hn;
  }
  #pragma unroll
  for (int off = 32; off > 0; off >>= 1) {
    sum += __shfl_xor(sum, off);
    sq  += __shfl_xor(sq,  off);
  }
  __shared__ float s1[4], s2[4];
  if ((tid & 63) == 0) { s1[tid >> 6] = sum; s2[tid >> 6] = sq; }
  __syncthreads();
  sum = s1[0] + s1[1] + s1[2] + s1[3];
  sq  = s2[0] + s2[1] + s2[2] + s2[3];
  const float mu  = sum * (1.f / 512.f);
  float var = sq * (1.f / 512.f) - mu * mu;
  var = fmaxf(var, 0.f);
  const float inv = rsqrtf(var + 1e-5f);
  #pragma unroll
  for (int l = 0; l < 2; ++l) {
    int d = tid + l * 256;
    out[row * 512 + d] = (val[l] - mu) * inv * ln_g[d] + ln_b[d];
  }
}

// ---------------------------------------------------------------------------
extern "C" void kernel_launch(void* const* d_in, const int* in_sizes, int n_in,
                              void* d_out, int out_size, void* d_ws, size_t ws_size,
                              hipStream_t stream) {
  (void)in_sizes; (void)n_in; (void)out_size; (void)ws_size;
  const float* inputs   = (const float*)d_in[0];
  const float* memory   = (const float*)d_in[1];
  const int*   graph    = (const int*)  d_in[2];
  const float* w_head_w = (const float*)d_in[3];
  const float* w_head_b = (const float*)d_in[4];
  const float* w_tail_w = (const float*)d_in[5];
  const float* w_tail_b = (const float*)d_in[6];
  const float* w_info_w = (const float*)d_in[7];
  const float* w_info_b = (const float*)d_in[8];
  const float* w_comb_w = (const float*)d_in[9];
  const float* w_comb_b = (const float*)d_in[10];
  const float* gru_w_ih = (const float*)d_in[11];
  const float* gru_w_hh = (const float*)d_in[12];
  const float* gru_b_ih = (const float*)d_in[13];
  const float* gru_b_hh = (const float*)d_in[14];
  const float* ln_g     = (const float*)d_in[15];
  const float* ln_b     = (const float*)d_in[16];
  float* out = (float*)d_out;

  // ---- workspace layout (byte offsets, 120 MiB used) ----
  char* W = (char*)d_ws;
  const size_t MB = 1u << 20;
  u16* in_hi  = (u16*)(W + 0 * MB);      // live: head GEMM, gi GEMM
  u16* in_lo  = (u16*)(W + 8 * MB);
  u16* mem_hi = (u16*)(W + 16 * MB);     // live: tail/info GEMMs
  u16* mem_lo = (u16*)(W + 24 * MB);
  u16* hb_hi  = mem_hi;                  // reuse after attn: comb out
  u16* hb_lo  = mem_lo;
  u16* wh_hi  = (u16*)(W + 32 * MB);     // weights 10MB: 32..42
  u16* wh_lo  = wh_hi + 262144;
  u16* wt_hi  = wh_lo + 262144;
  u16* wt_lo  = wt_hi + 262144;
  u16* wi_hi  = wt_lo + 262144;
  u16* wi_lo  = wi_hi + 262144;
  u16* wc_hi  = wi_lo + 262144;
  u16* wc_lo  = wc_hi + 262144;
  u16* wih_hi = wc_lo + 262144;
  u16* wih_lo = wih_hi + 786432;
  u16* whh_hi = wih_lo + 786432;
  u16* whh_lo = whh_hi + 786432;
  unsigned* bitsW = (unsigned*)(W + 42 * MB);  // 1MB packed graph
  u16* head_bf = (u16*)(W + 48 * MB);    // 8MB, dead after attn
  u16* tail_bf = (u16*)(W + 56 * MB);    // 8MB, dead after attn
  u16* VtB     = (u16*)(W + 64 * MB);    // 8MB, dead after attn
  u16* attn_hi = (u16*)(W + 72 * MB);    // 8MB, dead after comb
  u16* attn_lo = (u16*)(W + 80 * MB);
  float* giF   = (float*)(W + 48 * MB);  // 48MB (48..96), AFTER comb only
  u16* ghB     = (u16*)(W + 96 * MB);    // 24MB (96..120)

  const dim3 blk(256);
  const int nTok = NTOK * DMODEL;        // 4,194,304
  const float inv_scale = 0.04419417382415922f;  // 1/sqrt(512)

  // splits + mask pack
  split_f32<<<dim3(nTok / 1024), blk, 0, stream>>>(inputs, in_hi, in_lo, nTok);
  split_f32<<<dim3(nTok / 1024), blk, 0, stream>>>(memory, mem_hi, mem_lo, nTok);
  split_f32<<<dim3(256), blk, 0, stream>>>(w_head_w, wh_hi, wh_lo, 262144);
  split_f32<<<dim3(256), blk, 0, stream>>>(w_tail_w, wt_hi, wt_lo, 262144);
  split_f32<<<dim3(256), blk, 0, stream>>>(w_info_w, wi_hi, wi_lo, 262144);
  split_f32<<<dim3(256), blk, 0, stream>>>(w_comb_w, wc_hi, wc_lo, 262144);
  split_f32<<<dim3(768), blk, 0, stream>>>(gru_w_ih, wih_hi, wih_lo, 786432);
  split_f32<<<dim3(768), blk, 0, stream>>>(gru_w_hh, whh_hi, whh_lo, 786432);
  pack_graph<<<dim3(1024), blk, 0, stream>>>(graph, bitsW);

  // projections: head bf16 (scale folded), tail bf16, info transposed bf16
  gemm_mfma<1><<<dim3(8, 64), blk, 0, stream>>>(in_hi,  in_lo,  wh_hi, wh_lo, w_head_b, nullptr, head_bf, nullptr, inv_scale, 512);
  gemm_mfma<1><<<dim3(8, 64), blk, 0, stream>>>(mem_hi, mem_lo, wt_hi, wt_lo, w_tail_b, nullptr, tail_bf, nullptr, 1.0f, 512);
  gemm_mfma<3><<<dim3(8, 64), blk, 0, stream>>>(mem_hi, mem_lo, wi_hi, wi_lo, w_info_b, nullptr, VtB,     nullptr, 1.0f, 512);

  // MFMA flash attention -> split bf16 output
  attn_mfma<<<dim3(8, 64), blk, 0, stream>>>(head_bf, tail_bf, VtB, bitsW, attn_hi, attn_lo);

  // comb -> hbuf (split out)
  gemm_mfma<2><<<dim3(8, 64), blk, 0, stream>>>(attn_hi, attn_lo, wc_hi, wc_lo, w_comb_b, nullptr, hb_hi, hb_lo, 1.0f, 512);

  // GRU gate GEMMs (gh bf16; gi fp32 — giF clobbers head/tail/Vt/attn region)
  gemm_mfma<1><<<dim3(24, 64), blk, 0, stream>>>(hb_hi, hb_lo, whh_hi, whh_lo, gru_b_hh, nullptr, ghB, nullptr, 1.0f, 1536);
  gemm_mfma<0><<<dim3(24, 64), blk, 0, stream>>>(in_hi, in_lo, wih_hi, wih_lo, gru_b_ih, giF, nullptr, nullptr, 1.0f, 1536);

  // fused GRU + LayerNorm
  gru_ln_kernel<<<dim3(8192), blk, 0, stream>>>(giF, ghB, hb_hi, hb_lo, ln_g, ln_b, out);
}

// Round 9
// 353.198 us; speedup vs baseline: 2.7799x; 1.2533x over previous
//
#include <hip/hip_runtime.h>

#define NEGF (-1e30f)
#define NTOK 8192          // B*N
#define DMODEL 512
#define KDIM 512
#define NB 1024            // N
#define BATCH 8

typedef unsigned short u16;
typedef short bf16x8 __attribute__((ext_vector_type(8)));
typedef float f32x4 __attribute__((ext_vector_type(4)));

__device__ __forceinline__ float b2f(u16 u) {
  union { float f; unsigned int i; } c; c.i = ((unsigned int)u) << 16; return c.f;
}
__device__ __forceinline__ u16 f2b(float f) {   // RN-even
  union { float f; unsigned int i; } c; c.f = f;
  unsigned int r = c.i + 0x7fffu + ((c.i >> 16) & 1u);
  return (u16)(r >> 16);
}

// async global->LDS, 16B/lane; LDS dest is wave-uniform base + lane*16 (linear)
__device__ __forceinline__ void gload_lds16(const void* g, void* l) {
  __builtin_amdgcn_global_load_lds((const __attribute__((address_space(1))) void*)g,
                                   (__attribute__((address_space(3))) void*)l, 16, 0, 0);
}

// ---------------------------------------------------------------------------
// split fp32 -> (hi, lo) bf16 pair;  cast fp32 -> bf16 (hi only).
// ---------------------------------------------------------------------------
__global__ __launch_bounds__(256) void split_f32(
    const float* __restrict__ x, u16* __restrict__ hi, u16* __restrict__ lo, int n)
{
  int i = (blockIdx.x * 256 + threadIdx.x) * 4;
  if (i >= n) return;
  float4 v = *(const float4*)(x + i);
  ushort4 h, l;
  h.x = f2b(v.x); l.x = f2b(v.x - b2f(h.x));
  h.y = f2b(v.y); l.y = f2b(v.y - b2f(h.y));
  h.z = f2b(v.z); l.z = f2b(v.z - b2f(h.z));
  h.w = f2b(v.w); l.w = f2b(v.w - b2f(h.w));
  *(ushort4*)(hi + i) = h;
  *(ushort4*)(lo + i) = l;
}

__global__ __launch_bounds__(256) void cast_bf16(
    const float* __restrict__ x, u16* __restrict__ hi, int n)
{
  int i = (blockIdx.x * 256 + threadIdx.x) * 4;
  if (i >= n) return;
  float4 v = *(const float4*)(x + i);
  ushort4 h;
  h.x = f2b(v.x); h.y = f2b(v.y); h.z = f2b(v.z); h.w = f2b(v.w);
  *(ushort4*)(hi + i) = h;
}

// ---------------------------------------------------------------------------
// pack graph (int32 0/1, [B][N][N]) -> bitmask [B][N][N/32]  (32MB -> 1MB)
// ---------------------------------------------------------------------------
__global__ __launch_bounds__(256) void pack_graph(
    const int* __restrict__ g, unsigned* __restrict__ bits)
{
  const long w = (long)blockIdx.x * 256 + threadIdx.x;   // 262144 words
  const int* p = g + w * 32;
  unsigned m = 0;
  #pragma unroll
  for (int j = 0; j < 8; ++j) {
    int4 v = *(const int4*)(p + j * 4);
    m |= (v.x != 0 ? 1u : 0u) << (j * 4 + 0);
    m |= (v.y != 0 ? 1u : 0u) << (j * 4 + 1);
    m |= (v.z != 0 ? 1u : 0u) << (j * 4 + 2);
    m |= (v.w != 0 ? 1u : 0u) << (j * 4 + 3);
  }
  bits[w] = m;
}

// ---------------------------------------------------------------------------
// bf16 MFMA GEMM:  C[m,n] = sum_k A[m,k]*W[n,k] + bias[n]
// PASSES=3: split-bf16 (hi,lo) inputs, fp32-quality (bf16x3).
// PASSES=1: hi-only inputs (use when output is bf16-rounded anyway).
// MODE 0: fp32 out; 1: bf16 out (scaled); 2: split (hi,lo) out;
// MODE 3: transposed bf16 out into Vt[b*8+h][d][tok].
// XCD-swizzled block remap: same-A-panel blocks co-locate on one XCD's L2.
// ---------------------------------------------------------------------------
template<int MODE, int PASSES>
__global__ __launch_bounds__(256) void gemm_mfma(
    const u16* __restrict__ Ahi, const u16* __restrict__ Alo,
    const u16* __restrict__ Whi, const u16* __restrict__ Wlo,
    const float* __restrict__ bias,
    float* __restrict__ outF, u16* __restrict__ outB, u16* __restrict__ outL,
    float scale, int Ndim)
{
  constexpr int OFF_AL = 8192;
  constexpr int OFF_BH = (PASSES == 1) ? 8192 : 16384;
  constexpr int OFF_BL = 20480;
  __shared__ char smem[(PASSES == 1) ? 12288 : 24576];
  const int tid  = threadIdx.x;
  const int wave = tid >> 6, lane = tid & 63;
  const int wr = wave >> 1, wc = wave & 1;
  const int lrow = lane & 15, kg = lane >> 4;

  // XCD-aware bijective swizzle (grid totals are multiples of 8)
  const int tot = gridDim.x * gridDim.y;
  int bid = blockIdx.y * gridDim.x + blockIdx.x;
  int wg  = (bid & 7) * (tot >> 3) + (bid >> 3);
  const int bx = wg % gridDim.x, by = wg / gridDim.x;
  const int row0 = by * 128, col0 = bx * 64;

  const int sA0 = tid, sA1 = 256 + tid;
  const int rA0 = sA0 >> 2, rA1 = sA1 >> 2;
  const int cA0 = ((sA0 & 3) ^ (rA0 & 3)) * 8;
  const int cA1 = ((sA1 & 3) ^ (rA1 & 3)) * 8;
  const int rB  = tid >> 2;
  const int cB  = ((tid & 3) ^ (rB & 3)) * 8;

  const long arow0 = (long)row0 * KDIM;
  const long brow0 = (long)col0 * KDIM;

  f32x4 acc[4][2];
  #pragma unroll
  for (int m = 0; m < 4; ++m)
    #pragma unroll
    for (int n = 0; n < 2; ++n) acc[m][n] = (f32x4){0.f, 0.f, 0.f, 0.f};

  const int swz = ((kg ^ (lrow & 3)) << 4);

  for (int k0 = 0; k0 < KDIM; k0 += 32) {
    gload_lds16(Ahi + arow0 + (long)rA0 * KDIM + k0 + cA0, smem + sA0 * 16);
    gload_lds16(Ahi + arow0 + (long)rA1 * KDIM + k0 + cA1, smem + sA1 * 16);
    gload_lds16(Whi + brow0 + (long)rB * KDIM + k0 + cB, smem + OFF_BH + tid * 16);
    if constexpr (PASSES == 3) {
      gload_lds16(Alo + arow0 + (long)rA0 * KDIM + k0 + cA0, smem + OFF_AL + sA0 * 16);
      gload_lds16(Alo + arow0 + (long)rA1 * KDIM + k0 + cA1, smem + OFF_AL + sA1 * 16);
      gload_lds16(Wlo + brow0 + (long)rB * KDIM + k0 + cB, smem + OFF_BL + tid * 16);
    }
    __syncthreads();

    bf16x8 ah[4], bh[2];
    #pragma unroll
    for (int m = 0; m < 4; ++m) {
      const int r = wr * 64 + m * 16 + lrow;
      ah[m] = *(const bf16x8*)(smem + r * 64 + swz);
    }
    #pragma unroll
    for (int n = 0; n < 2; ++n) {
      const int r = wc * 32 + n * 16 + lrow;
      bh[n] = *(const bf16x8*)(smem + OFF_BH + r * 64 + swz);
    }
    #pragma unroll
    for (int m = 0; m < 4; ++m)
      #pragma unroll
      for (int n = 0; n < 2; ++n)
        acc[m][n] = __builtin_amdgcn_mfma_f32_16x16x32_bf16(ah[m], bh[n], acc[m][n], 0, 0, 0);
    if constexpr (PASSES == 3) {
      bf16x8 al[4], bl[2];
      #pragma unroll
      for (int m = 0; m < 4; ++m) {
        const int r = wr * 64 + m * 16 + lrow;
        al[m] = *(const bf16x8*)(smem + OFF_AL + r * 64 + swz);
      }
      #pragma unroll
      for (int n = 0; n < 2; ++n) {
        const int r = wc * 32 + n * 16 + lrow;
        bl[n] = *(const bf16x8*)(smem + OFF_BL + r * 64 + swz);
      }
      #pragma unroll
      for (int m = 0; m < 4; ++m)
        #pragma unroll
        for (int n = 0; n < 2; ++n) {
          acc[m][n] = __builtin_amdgcn_mfma_f32_16x16x32_bf16(ah[m], bl[n], acc[m][n], 0, 0, 0);
          acc[m][n] = __builtin_amdgcn_mfma_f32_16x16x32_bf16(al[m], bh[n], acc[m][n], 0, 0, 0);
        }
    }
    __syncthreads();
  }

  // epilogue: C/D map col=lane&15, row=(lane>>4)*4+q
  #pragma unroll
  for (int m = 0; m < 4; ++m) {
    const int grow = row0 + wr * 64 + m * 16 + kg * 4;
    #pragma unroll
    for (int n = 0; n < 2; ++n) {
      const int gcol = col0 + wc * 32 + n * 16 + lrow;
      const float bv = bias[gcol];
      #pragma unroll
      for (int q = 0; q < 4; ++q) {
        const float v = acc[m][n][q] + bv;
        if constexpr (MODE == 0) {
          outF[(long)(grow + q) * Ndim + gcol] = v;
        } else if constexpr (MODE == 1) {
          outB[(long)(grow + q) * Ndim + gcol] = f2b(v * scale);
        } else if constexpr (MODE == 2) {
          const u16 hb = f2b(v);
          outB[(long)(grow + q) * Ndim + gcol] = hb;
          outL[(long)(grow + q) * Ndim + gcol] = f2b(v - b2f(hb));
        } else {  // MODE 3: Vt[(b*8+h)][d][tok]
          const int tok = (grow + q) & 1023;
          const int bb  = (grow + q) >> 10;
          const int hh  = gcol >> 6;
          const int dd  = gcol & 63;
          outB[(((long)(bb * 8 + hh)) * 64 + dd) * 1024 + tok] = f2b(v);
        }
      }
    }
  }
}

// ---------------------------------------------------------------------------
// MFMA flash attention, fixed-max softmax (M0=1; scores bounded ~|s|<=1 so
// exp never overflows; masked p=0 exactly; denominators accumulate lane-
// locally, one 4-shfl reduce at the end). XCD-swizzled for K/V L2 reuse.
// ---------------------------------------------------------------------------
__global__ __launch_bounds__(256) void attn_mfma(
    const u16* __restrict__ Qb, const u16* __restrict__ Kb,
    const u16* __restrict__ Vt, const unsigned* __restrict__ bits,
    u16* __restrict__ ohi, u16* __restrict__ olo)
{
  // swizzle: grid (8,64) -> XCD k gets 8 consecutive bh values
  int bid0 = blockIdx.y * 8 + blockIdx.x;
  int wg   = (bid0 & 7) * 64 + (bid0 >> 3);
  const int bh = wg >> 3;
  const int b  = bh >> 3, h = bh & 7;
  const int n0 = (wg & 7) * 128;
  const int tid = threadIdx.x, wid = tid >> 6, lane = tid & 63;
  const int lx = lane & 15, kg = lane >> 4;

  __shared__ char lds[32768];            // K 8K | Vt 8K | P 16K (4K/wave)
  char* Kl = lds;
  char* Vl = lds + 8192;
  char* Pl = lds + 16384 + wid * 4096;

  // Q frags: A-layout, rows n0+wid*32+m*16+lx, k-octet kg within 32-step
  bf16x8 qf[2][2];
  #pragma unroll
  for (int m = 0; m < 2; ++m)
    #pragma unroll
    for (int ks = 0; ks < 2; ++ks)
      qf[m][ks] = *(const bf16x8*)(Qb +
          (long)(b * NB + n0 + wid * 32 + m * 16 + lx) * DMODEL +
          h * 64 + ks * 32 + kg * 8);

  f32x4 o[2][4];
  float lsum[2][4];
  #pragma unroll
  for (int m = 0; m < 2; ++m)
    #pragma unroll
    for (int n = 0; n < 4; ++n) o[m][n] = (f32x4){0.f, 0.f, 0.f, 0.f};
  #pragma unroll
  for (int m = 0; m < 2; ++m)
    #pragma unroll
    for (int q = 0; q < 4; ++q) lsum[m][q] = 0.f;

  const int s0 = tid, s1 = 256 + tid;
  const int r0 = s0 >> 3, c0 = (s0 & 7) ^ (r0 & 7);
  const int r1 = s1 >> 3, c1 = (s1 & 7) ^ (r1 & 7);
  const u16* Kg = Kb + (long)(b * NB) * DMODEL + h * 64;  // row stride 512
  const u16* Vg = Vt + (long)bh * 64 * 1024;              // d-row stride 1024

  for (int t = 0; t < 16; ++t) {
    const int m0 = t * 64;
    __syncthreads();
    gload_lds16(Kg + (long)(m0 + r0) * DMODEL + c0 * 8, Kl + s0 * 16);
    gload_lds16(Kg + (long)(m0 + r1) * DMODEL + c1 * 8, Kl + s1 * 16);
    gload_lds16(Vg + (long)r0 * 1024 + m0 + c0 * 8, Vl + s0 * 16);
    gload_lds16(Vg + (long)r1 * 1024 + m0 + c1 * 8, Vl + s1 * 16);
    __syncthreads();

    // ---- S = Q K^T (scale folded into Q) ----
    bf16x8 kf[4][2];
    #pragma unroll
    for (int n = 0; n < 4; ++n)
      #pragma unroll
      for (int ks = 0; ks < 2; ++ks) {
        const int col = n * 16 + lx;
        const int slot = ks * 4 + kg;
        kf[n][ks] = *(const bf16x8*)(Kl + col * 128 + ((slot ^ (col & 7)) << 4));
      }
    f32x4 s[2][4];
    #pragma unroll
    for (int m = 0; m < 2; ++m)
      #pragma unroll
      for (int n = 0; n < 4; ++n) {
        s[m][n] = (f32x4){0.f, 0.f, 0.f, 0.f};
        s[m][n] = __builtin_amdgcn_mfma_f32_16x16x32_bf16(qf[m][0], kf[n][0], s[m][n], 0, 0, 0);
        s[m][n] = __builtin_amdgcn_mfma_f32_16x16x32_bf16(qf[m][1], kf[n][1], s[m][n], 0, 0, 0);
      }

    // ---- mask + fixed-max softmax numerators ----
    u16 pb[2][4][4];
    #pragma unroll
    for (int m = 0; m < 2; ++m) {
      const unsigned* bp = bits +
          ((long)(b * NB + n0 + wid * 32 + m * 16 + kg * 4)) * 32 + (m0 >> 5);
      #pragma unroll
      for (int q = 0; q < 4; ++q) {
        const uint2 w = *(const uint2*)(bp + q * 32);
        float acc_l = 0.f;
        #pragma unroll
        for (int n = 0; n < 4; ++n) {
          const unsigned wd = (n & 2) ? w.y : w.x;
          const int sh = (n & 1) * 16 + lx;
          const float p = ((wd >> sh) & 1u) ? __expf(s[m][n][q] - 1.0f) : 0.f;
          acc_l += p;
          pb[m][n][q] = f2b(p);
        }
        lsum[m][q] += acc_l;
      }
    }

    // ---- P: C-layout -> per-wave LDS (XOR-swizzled) -> A-layout ----
    #pragma unroll
    for (int m = 0; m < 2; ++m)
      #pragma unroll
      for (int n = 0; n < 4; ++n)
        #pragma unroll
        for (int q = 0; q < 4; ++q) {
          const int row = m * 16 + kg * 4 + q;
          *(u16*)(Pl + row * 128 + ((n * 32 + lx * 2) ^ ((row & 7) << 4))) =
              pb[m][n][q];
        }
    bf16x8 pf[2][2], vf[4][2];
    #pragma unroll
    for (int m = 0; m < 2; ++m)
      #pragma unroll
      for (int ks = 0; ks < 2; ++ks) {
        const int row = m * 16 + lx;
        const int slot = ks * 4 + kg;
        pf[m][ks] = *(const bf16x8*)(Pl + row * 128 + ((slot ^ (row & 7)) << 4));
      }
    #pragma unroll
    for (int n = 0; n < 4; ++n)
      #pragma unroll
      for (int ks = 0; ks < 2; ++ks) {
        const int col = n * 16 + lx;
        const int slot = ks * 4 + kg;
        vf[n][ks] = *(const bf16x8*)(Vl + col * 128 + ((slot ^ (col & 7)) << 4));
      }
    #pragma unroll
    for (int m = 0; m < 2; ++m)
      #pragma unroll
      for (int n = 0; n < 4; ++n) {
        o[m][n] = __builtin_amdgcn_mfma_f32_16x16x32_bf16(pf[m][0], vf[n][0], o[m][n], 0, 0, 0);
        o[m][n] = __builtin_amdgcn_mfma_f32_16x16x32_bf16(pf[m][1], vf[n][1], o[m][n], 0, 0, 0);
      }
  }

  // ---- epilogue: row-denominator reduce, O/l, split hi/lo ----
  #pragma unroll
  for (int m = 0; m < 2; ++m)
    #pragma unroll
    for (int q = 0; q < 4; ++q) {
      float l = lsum[m][q];
      l += __shfl_xor(l, 1);
      l += __shfl_xor(l, 2);
      l += __shfl_xor(l, 4);
      l += __shfl_xor(l, 8);
      const float inv = 1.f / l;     // >=1 unmasked entry (self-loop)
      const long rowg = (long)(b * NB + n0 + wid * 32 + m * 16 + kg * 4 + q);
      #pragma unroll
      for (int n = 0; n < 4; ++n) {
        const long idx = rowg * DMODEL + h * 64 + n * 16 + lx;
        const float v = o[m][n][q] * inv;
        const u16 hb = f2b(v);
        ohi[idx] = hb;
        olo[idx] = f2b(v - b2f(hb));
      }
    }
}

// ---------------------------------------------------------------------------
// Fused GRU + LayerNorm. gi fp32, gh bf16, h = hbuf_hi + hbuf_lo.
// ---------------------------------------------------------------------------
__global__ __launch_bounds__(256) void gru_ln_kernel(
    const float* __restrict__ gi, const u16* __restrict__ gh,
    const u16* __restrict__ hhi, const u16* __restrict__ hlo,
    const float* __restrict__ ln_g, const float* __restrict__ ln_b,
    float* __restrict__ out)
{
  const long row = blockIdx.x;
  const int tid = threadIdx.x;
  const float* gir = gi + row * 1536;
  const u16*   ghr = gh + row * 1536;

  float val[2];
  float sum = 0.f, sq = 0.f;
  #pragma unroll
  for (int l = 0; l < 2; ++l) {
    int d = tid + l * 256;
    float r = 1.f / (1.f + __expf(-(gir[d] + b2f(ghr[d]))));
    float z = 1.f / (1.f + __expf(-(gir[512 + d] + b2f(ghr[512 + d]))));
    float n = tanhf(gir[1024 + d] + r * b2f(ghr[1024 + d]));
    float hv = b2f(hhi[row * 512 + d]) + b2f(hlo[row * 512 + d]);
    float hn = (1.f - z) * n + z * hv;
    val[l] = hn; sum += hn; sq += hn * hn;
  }
  #pragma unroll
  for (int off = 32; off > 0; off >>= 1) {
    sum += __shfl_xor(sum, off);
    sq  += __shfl_xor(sq,  off);
  }
  __shared__ float s1[4], s2[4];
  if ((tid & 63) == 0) { s1[tid >> 6] = sum; s2[tid >> 6] = sq; }
  __syncthreads();
  sum = s1[0] + s1[1] + s1[2] + s1[3];
  sq  = s2[0] + s2[1] + s2[2] + s2[3];
  const float mu  = sum * (1.f / 512.f);
  float var = sq * (1.f / 512.f) - mu * mu;
  var = fmaxf(var, 0.f);
  const float inv = rsqrtf(var + 1e-5f);
  #pragma unroll
  for (int l = 0; l < 2; ++l) {
    int d = tid + l * 256;
    out[row * 512 + d] = (val[l] - mu) * inv * ln_g[d] + ln_b[d];
  }
}

// ---------------------------------------------------------------------------
extern "C" void kernel_launch(void* const* d_in, const int* in_sizes, int n_in,
                              void* d_out, int out_size, void* d_ws, size_t ws_size,
                              hipStream_t stream) {
  (void)in_sizes; (void)n_in; (void)out_size; (void)ws_size;
  const float* inputs   = (const float*)d_in[0];
  const float* memory   = (const float*)d_in[1];
  const int*   graph    = (const int*)  d_in[2];
  const float* w_head_w = (const float*)d_in[3];
  const float* w_head_b = (const float*)d_in[4];
  const float* w_tail_w = (const float*)d_in[5];
  const float* w_tail_b = (const float*)d_in[6];
  const float* w_info_w = (const float*)d_in[7];
  const float* w_info_b = (const float*)d_in[8];
  const float* w_comb_w = (const float*)d_in[9];
  const float* w_comb_b = (const float*)d_in[10];
  const float* gru_w_ih = (const float*)d_in[11];
  const float* gru_w_hh = (const float*)d_in[12];
  const float* gru_b_ih = (const float*)d_in[13];
  const float* gru_b_hh = (const float*)d_in[14];
  const float* ln_g     = (const float*)d_in[15];
  const float* ln_b     = (const float*)d_in[16];
  float* out = (float*)d_out;

  // ---- workspace layout (byte offsets, 120 MiB used) ----
  char* W = (char*)d_ws;
  const size_t MB = 1u << 20;
  u16* in_hi  = (u16*)(W + 0 * MB);      // live: head GEMM, gi GEMM
  u16* in_lo  = (u16*)(W + 8 * MB);
  u16* mem_hi = (u16*)(W + 16 * MB);     // live: tail/info GEMMs
  u16* hb_hi  = mem_hi;                  // reuse after attn: comb out
  u16* hb_lo  = (u16*)(W + 24 * MB);
  u16* wh_hi  = (u16*)(W + 32 * MB);     // weights 10MB: 32..42
  u16* wh_lo  = wh_hi + 262144;          // (lo slots unused for 1-pass weights)
  u16* wt_hi  = wh_lo + 262144;
  u16* wt_lo  = wt_hi + 262144;
  u16* wi_hi  = wt_lo + 262144;
  u16* wi_lo  = wi_hi + 262144;
  u16* wc_hi  = wi_lo + 262144;
  u16* wc_lo  = wc_hi + 262144;
  u16* wih_hi = wc_lo + 262144;
  u16* wih_lo = wih_hi + 786432;
  u16* whh_hi = wih_lo + 786432;
  unsigned* bitsW = (unsigned*)(W + 42 * MB);  // 1MB packed graph
  u16* head_bf = (u16*)(W + 48 * MB);    // 8MB, dead after attn
  u16* tail_bf = (u16*)(W + 56 * MB);    // 8MB, dead after attn
  u16* VtB     = (u16*)(W + 64 * MB);    // 8MB, dead after attn
  u16* attn_hi = (u16*)(W + 72 * MB);    // 8MB, dead after comb
  u16* attn_lo = (u16*)(W + 80 * MB);
  float* giF   = (float*)(W + 48 * MB);  // 48MB (48..96), AFTER comb only
  u16* ghB     = (u16*)(W + 96 * MB);    // 24MB (96..120)

  const dim3 blk(256);
  const int nTok = NTOK * DMODEL;        // 4,194,304
  const float inv_scale = 0.04419417382415922f;  // 1/sqrt(512)

  // casts/splits + mask pack (split only where a 3-pass GEMM consumes lo)
  split_f32<<<dim3(nTok / 1024), blk, 0, stream>>>(inputs, in_hi, in_lo, nTok);
  cast_bf16<<<dim3(nTok / 1024), blk, 0, stream>>>(memory, mem_hi, nTok);
  cast_bf16<<<dim3(256), blk, 0, stream>>>(w_head_w, wh_hi, 262144);
  cast_bf16<<<dim3(256), blk, 0, stream>>>(w_tail_w, wt_hi, 262144);
  cast_bf16<<<dim3(256), blk, 0, stream>>>(w_info_w, wi_hi, 262144);
  split_f32<<<dim3(256), blk, 0, stream>>>(w_comb_w, wc_hi, wc_lo, 262144);
  split_f32<<<dim3(768), blk, 0, stream>>>(gru_w_ih, wih_hi, wih_lo, 786432);
  cast_bf16<<<dim3(768), blk, 0, stream>>>(gru_w_hh, whh_hi, 786432);
  pack_graph<<<dim3(1024), blk, 0, stream>>>(graph, bitsW);

  // projections: 1-pass (outputs are bf16-rounded anyway; input-split gain
  // would be below the output rounding). head gets 1/sqrt(D) folded in.
  gemm_mfma<1, 1><<<dim3(8, 64), blk, 0, stream>>>(in_hi,  nullptr, wh_hi, nullptr, w_head_b, nullptr, head_bf, nullptr, inv_scale, 512);
  gemm_mfma<1, 1><<<dim3(8, 64), blk, 0, stream>>>(mem_hi, nullptr, wt_hi, nullptr, w_tail_b, nullptr, tail_bf, nullptr, 1.0f, 512);
  gemm_mfma<3, 1><<<dim3(8, 64), blk, 0, stream>>>(mem_hi, nullptr, wi_hi, nullptr, w_info_b, nullptr, VtB,     nullptr, 1.0f, 512);

  // MFMA flash attention -> split bf16 output
  attn_mfma<<<dim3(8, 64), blk, 0, stream>>>(head_bf, tail_bf, VtB, bitsW, attn_hi, attn_lo);

  // comb -> hbuf: 3-pass (h enters the output linearly; keep fp32 quality)
  gemm_mfma<2, 3><<<dim3(8, 64), blk, 0, stream>>>(attn_hi, attn_lo, wc_hi, wc_lo, w_comb_b, nullptr, hb_hi, hb_lo, 1.0f, 512);

  // GRU gates: gh 1-pass (bf16 out dominates), gi 3-pass fp32 out
  gemm_mfma<1, 1><<<dim3(24, 64), blk, 0, stream>>>(hb_hi, nullptr, whh_hi, nullptr, gru_b_hh, nullptr, ghB, nullptr, 1.0f, 1536);
  gemm_mfma<0, 3><<<dim3(24, 64), blk, 0, stream>>>(in_hi, in_lo, wih_hi, wih_lo, gru_b_ih, giF, nullptr, nullptr, 1.0f, 1536);

  // fused GRU + LayerNorm
  gru_ln_kernel<<<dim3(8192), blk, 0, stream>>>(giF, ghB, hb_hi, hb_lo, ln_g, ln_b, out);
}

// Round 13
// 299.240 us; speedup vs baseline: 3.2811x; 1.1803x over previous
//
#include <hip/hip_runtime.h>

#define NEGF (-1e30f)
#define NTOK 8192          // B*N
#define DMODEL 512
#define KDIM 512
#define NB 1024            // N
#define BATCH 8

typedef unsigned short u16;
typedef short bf16x8 __attribute__((ext_vector_type(8)));
typedef float f32x4 __attribute__((ext_vector_type(4)));

__device__ __forceinline__ float b2f(u16 u) {
  union { float f; unsigned int i; } c; c.i = ((unsigned int)u) << 16; return c.f;
}
__device__ __forceinline__ u16 f2b(float f) {   // RN-even
  union { float f; unsigned int i; } c; c.f = f;
  unsigned int r = c.i + 0x7fffu + ((c.i >> 16) & 1u);
  return (u16)(r >> 16);
}

// async global->LDS, 16B/lane; LDS dest is wave-uniform base + lane*16 (linear)
__device__ __forceinline__ void gload_lds16(const void* g, void* l) {
  __builtin_amdgcn_global_load_lds((const __attribute__((address_space(1))) void*)g,
                                   (__attribute__((address_space(3))) void*)l, 16, 0, 0);
}

// ---------------------------------------------------------------------------
// merged bf16 cast for all 8 fp32 tensors (1 launch instead of 8).
// block ranges: inputs 4096 | memory 4096 | wh 256 | wt 256 | wi 256 |
//               wc 256 | wih 768 | whh 768   (total 10752 blocks x 1024 elems)
// ---------------------------------------------------------------------------
__global__ __launch_bounds__(256) void cast_all(
    const float* __restrict__ s0, const float* __restrict__ s1,
    const float* __restrict__ s2, const float* __restrict__ s3,
    const float* __restrict__ s4, const float* __restrict__ s5,
    const float* __restrict__ s6, const float* __restrict__ s7,
    u16* __restrict__ d0, u16* __restrict__ d1, u16* __restrict__ d2,
    u16* __restrict__ d3, u16* __restrict__ d4, u16* __restrict__ d5,
    u16* __restrict__ d6, u16* __restrict__ d7)
{
  const int b = blockIdx.x;
  const float* s; u16* d; int rel;
  if      (b < 4096)  { s = s0; d = d0; rel = b; }
  else if (b < 8192)  { s = s1; d = d1; rel = b - 4096; }
  else if (b < 8448)  { s = s2; d = d2; rel = b - 8192; }
  else if (b < 8704)  { s = s3; d = d3; rel = b - 8448; }
  else if (b < 8960)  { s = s4; d = d4; rel = b - 8704; }
  else if (b < 9216)  { s = s5; d = d5; rel = b - 8960; }
  else if (b < 9984)  { s = s6; d = d6; rel = b - 9216; }
  else                { s = s7; d = d7; rel = b - 9984; }
  const int i = rel * 1024 + threadIdx.x * 4;
  float4 v = *(const float4*)(s + i);
  ushort4 h;
  h.x = f2b(v.x); h.y = f2b(v.y); h.z = f2b(v.z); h.w = f2b(v.w);
  *(ushort4*)(d + i) = h;
}

// ---------------------------------------------------------------------------
// pack graph (int32 0/1, [B][N][N]) -> bitmask [B][N][N/32]  (32MB -> 1MB)
// ---------------------------------------------------------------------------
__global__ __launch_bounds__(256) void pack_graph(
    const int* __restrict__ g, unsigned* __restrict__ bits)
{
  const long w = (long)blockIdx.x * 256 + threadIdx.x;   // 262144 words
  const int* p = g + w * 32;
  unsigned m = 0;
  #pragma unroll
  for (int j = 0; j < 8; ++j) {
    int4 v = *(const int4*)(p + j * 4);
    m |= (v.x != 0 ? 1u : 0u) << (j * 4 + 0);
    m |= (v.y != 0 ? 1u : 0u) << (j * 4 + 1);
    m |= (v.z != 0 ? 1u : 0u) << (j * 4 + 2);
    m |= (v.w != 0 ? 1u : 0u) << (j * 4 + 3);
  }
  bits[w] = m;
}

// ---------------------------------------------------------------------------
// bf16 MFMA GEMM:  C[m,n] = sum_k A[m,k]*W[n,k] + bias[n]   (1-pass bf16)
// MODE 1: bf16 out (scaled); 2: split (hi,lo) out;
// MODE 3: transposed bf16 out into Vt[b*8+h][d][tok].
// XCD-swizzled block remap; BM=128 BN=64 BK=32, 4 waves, 12KB LDS.
// ---------------------------------------------------------------------------
template<int MODE>
__global__ __launch_bounds__(256) void gemm_mfma(
    const u16* __restrict__ A, const u16* __restrict__ Wt,
    const float* __restrict__ bias,
    u16* __restrict__ outB, u16* __restrict__ outL,
    float scale, int Ndim)
{
  constexpr int OFF_B = 8192;
  __shared__ char smem[12288];
  const int tid  = threadIdx.x;
  const int wave = tid >> 6, lane = tid & 63;
  const int wr = wave >> 1, wc = wave & 1;
  const int lrow = lane & 15, kg = lane >> 4;

  // XCD-aware bijective swizzle (grid totals are multiples of 8)
  const int tot = gridDim.x * gridDim.y;
  int bid = blockIdx.y * gridDim.x + blockIdx.x;
  int wg  = (bid & 7) * (tot >> 3) + (bid >> 3);
  const int bx = wg % gridDim.x, by = wg / gridDim.x;
  const int row0 = by * 128, col0 = bx * 64;

  const int sA0 = tid, sA1 = 256 + tid;
  const int rA0 = sA0 >> 2, rA1 = sA1 >> 2;
  const int cA0 = ((sA0 & 3) ^ (rA0 & 3)) * 8;
  const int cA1 = ((sA1 & 3) ^ (rA1 & 3)) * 8;
  const int rB  = tid >> 2;
  const int cB  = ((tid & 3) ^ (rB & 3)) * 8;

  const long arow0 = (long)row0 * KDIM;
  const long brow0 = (long)col0 * KDIM;

  f32x4 acc[4][2];
  #pragma unroll
  for (int m = 0; m < 4; ++m)
    #pragma unroll
    for (int n = 0; n < 2; ++n) acc[m][n] = (f32x4){0.f, 0.f, 0.f, 0.f};

  const int swz = ((kg ^ (lrow & 3)) << 4);

  for (int k0 = 0; k0 < KDIM; k0 += 32) {
    gload_lds16(A + arow0 + (long)rA0 * KDIM + k0 + cA0, smem + sA0 * 16);
    gload_lds16(A + arow0 + (long)rA1 * KDIM + k0 + cA1, smem + sA1 * 16);
    gload_lds16(Wt + brow0 + (long)rB * KDIM + k0 + cB, smem + OFF_B + tid * 16);
    __syncthreads();

    bf16x8 ah[4], bh[2];
    #pragma unroll
    for (int m = 0; m < 4; ++m) {
      const int r = wr * 64 + m * 16 + lrow;
      ah[m] = *(const bf16x8*)(smem + r * 64 + swz);
    }
    #pragma unroll
    for (int n = 0; n < 2; ++n) {
      const int r = wc * 32 + n * 16 + lrow;
      bh[n] = *(const bf16x8*)(smem + OFF_B + r * 64 + swz);
    }
    #pragma unroll
    for (int m = 0; m < 4; ++m)
      #pragma unroll
      for (int n = 0; n < 2; ++n)
        acc[m][n] = __builtin_amdgcn_mfma_f32_16x16x32_bf16(ah[m], bh[n], acc[m][n], 0, 0, 0);
    __syncthreads();
  }

  // epilogue: C/D map col=lane&15, row=(lane>>4)*4+q
  #pragma unroll
  for (int m = 0; m < 4; ++m) {
    const int grow = row0 + wr * 64 + m * 16 + kg * 4;
    #pragma unroll
    for (int n = 0; n < 2; ++n) {
      const int gcol = col0 + wc * 32 + n * 16 + lrow;
      const float bv = bias[gcol];
      #pragma unroll
      for (int q = 0; q < 4; ++q) {
        const float v = acc[m][n][q] + bv;
        if constexpr (MODE == 1) {
          outB[(long)(grow + q) * Ndim + gcol] = f2b(v * scale);
        } else if constexpr (MODE == 2) {
          const u16 hb = f2b(v);
          outB[(long)(grow + q) * Ndim + gcol] = hb;
          outL[(long)(grow + q) * Ndim + gcol] = f2b(v - b2f(hb));
        } else {  // MODE 3: Vt[(b*8+h)][d][tok]
          const int tok = (grow + q) & 1023;
          const int bb  = (grow + q) >> 10;
          const int hh  = gcol >> 6;
          const int dd  = gcol & 63;
          outB[(((long)(bb * 8 + hh)) * 64 + dd) * 1024 + tok] = f2b(v);
        }
      }
    }
  }
}

// ---------------------------------------------------------------------------
// MFMA flash attention, fixed-max softmax (M0=1; scores bounded, exp safe;
// masked p=0 exactly; lane-local denominators, one 4-shfl reduce at end).
// XCD-swizzled. bf16 output only (comb GEMM is 1-pass).
// ---------------------------------------------------------------------------
__global__ __launch_bounds__(256) void attn_mfma(
    const u16* __restrict__ Qb, const u16* __restrict__ Kb,
    const u16* __restrict__ Vt, const unsigned* __restrict__ bits,
    u16* __restrict__ ohi)
{
  // swizzle: grid (8,64) -> XCD k gets 8 consecutive bh values
  int bid0 = blockIdx.y * 8 + blockIdx.x;
  int wg   = (bid0 & 7) * 64 + (bid0 >> 3);
  const int bh = wg >> 3;
  const int b  = bh >> 3, h = bh & 7;
  const int n0 = (wg & 7) * 128;
  const int tid = threadIdx.x, wid = tid >> 6, lane = tid & 63;
  const int lx = lane & 15, kg = lane >> 4;

  __shared__ char lds[32768];            // K 8K | Vt 8K | P 16K (4K/wave)
  char* Kl = lds;
  char* Vl = lds + 8192;
  char* Pl = lds + 16384 + wid * 4096;

  // Q frags: A-layout, rows n0+wid*32+m*16+lx, k-octet kg within 32-step
  bf16x8 qf[2][2];
  #pragma unroll
  for (int m = 0; m < 2; ++m)
    #pragma unroll
    for (int ks = 0; ks < 2; ++ks)
      qf[m][ks] = *(const bf16x8*)(Qb +
          (long)(b * NB + n0 + wid * 32 + m * 16 + lx) * DMODEL +
          h * 64 + ks * 32 + kg * 8);

  f32x4 o[2][4];
  float lsum[2][4];
  #pragma unroll
  for (int m = 0; m < 2; ++m)
    #pragma unroll
    for (int n = 0; n < 4; ++n) o[m][n] = (f32x4){0.f, 0.f, 0.f, 0.f};
  #pragma unroll
  for (int m = 0; m < 2; ++m)
    #pragma unroll
    for (int q = 0; q < 4; ++q) lsum[m][q] = 0.f;

  const int s0 = tid, s1 = 256 + tid;
  const int r0 = s0 >> 3, c0 = (s0 & 7) ^ (r0 & 7);
  const int r1 = s1 >> 3, c1 = (s1 & 7) ^ (r1 & 7);
  const u16* Kg = Kb + (long)(b * NB) * DMODEL + h * 64;  // row stride 512
  const u16* Vg = Vt + (long)bh * 64 * 1024;              // d-row stride 1024

  for (int t = 0; t < 16; ++t) {
    const int m0 = t * 64;
    __syncthreads();
    gload_lds16(Kg + (long)(m0 + r0) * DMODEL + c0 * 8, Kl + s0 * 16);
    gload_lds16(Kg + (long)(m0 + r1) * DMODEL + c1 * 8, Kl + s1 * 16);
    gload_lds16(Vg + (long)r0 * 1024 + m0 + c0 * 8, Vl + s0 * 16);
    gload_lds16(Vg + (long)r1 * 1024 + m0 + c1 * 8, Vl + s1 * 16);
    __syncthreads();

    // ---- S = Q K^T (scale folded into Q) ----
    bf16x8 kf[4][2];
    #pragma unroll
    for (int n = 0; n < 4; ++n)
      #pragma unroll
      for (int ks = 0; ks < 2; ++ks) {
        const int col = n * 16 + lx;
        const int slot = ks * 4 + kg;
        kf[n][ks] = *(const bf16x8*)(Kl + col * 128 + ((slot ^ (col & 7)) << 4));
      }
    f32x4 s[2][4];
    #pragma unroll
    for (int m = 0; m < 2; ++m)
      #pragma unroll
      for (int n = 0; n < 4; ++n) {
        s[m][n] = (f32x4){0.f, 0.f, 0.f, 0.f};
        s[m][n] = __builtin_amdgcn_mfma_f32_16x16x32_bf16(qf[m][0], kf[n][0], s[m][n], 0, 0, 0);
        s[m][n] = __builtin_amdgcn_mfma_f32_16x16x32_bf16(qf[m][1], kf[n][1], s[m][n], 0, 0, 0);
      }

    // ---- mask + fixed-max softmax numerators ----
    u16 pb[2][4][4];
    #pragma unroll
    for (int m = 0; m < 2; ++m) {
      const unsigned* bp = bits +
          ((long)(b * NB + n0 + wid * 32 + m * 16 + kg * 4)) * 32 + (m0 >> 5);
      #pragma unroll
      for (int q = 0; q < 4; ++q) {
        const uint2 w = *(const uint2*)(bp + q * 32);
        float acc_l = 0.f;
        #pragma unroll
        for (int n = 0; n < 4; ++n) {
          const unsigned wd = (n & 2) ? w.y : w.x;
          const int sh = (n & 1) * 16 + lx;
          const float p = ((wd >> sh) & 1u) ? __expf(s[m][n][q] - 1.0f) : 0.f;
          acc_l += p;
          pb[m][n][q] = f2b(p);
        }
        lsum[m][q] += acc_l;
      }
    }

    // ---- P: C-layout -> per-wave LDS (XOR-swizzled) -> A-layout ----
    #pragma unroll
    for (int m = 0; m < 2; ++m)
      #pragma unroll
      for (int n = 0; n < 4; ++n)
        #pragma unroll
        for (int q = 0; q < 4; ++q) {
          const int row = m * 16 + kg * 4 + q;
          *(u16*)(Pl + row * 128 + ((n * 32 + lx * 2) ^ ((row & 7) << 4))) =
              pb[m][n][q];
        }
    bf16x8 pf[2][2], vf[4][2];
    #pragma unroll
    for (int m = 0; m < 2; ++m)
      #pragma unroll
      for (int ks = 0; ks < 2; ++ks) {
        const int row = m * 16 + lx;
        const int slot = ks * 4 + kg;
        pf[m][ks] = *(const bf16x8*)(Pl + row * 128 + ((slot ^ (row & 7)) << 4));
      }
    #pragma unroll
    for (int n = 0; n < 4; ++n)
      #pragma unroll
      for (int ks = 0; ks < 2; ++ks) {
        const int col = n * 16 + lx;
        const int slot = ks * 4 + kg;
        vf[n][ks] = *(const bf16x8*)(Vl + col * 128 + ((slot ^ (col & 7)) << 4));
      }
    #pragma unroll
    for (int m = 0; m < 2; ++m)
      #pragma unroll
      for (int n = 0; n < 4; ++n) {
        o[m][n] = __builtin_amdgcn_mfma_f32_16x16x32_bf16(pf[m][0], vf[n][0], o[m][n], 0, 0, 0);
        o[m][n] = __builtin_amdgcn_mfma_f32_16x16x32_bf16(pf[m][1], vf[n][1], o[m][n], 0, 0, 0);
      }
  }

  // ---- epilogue: row-denominator reduce, O/l, bf16 out ----
  #pragma unroll
  for (int m = 0; m < 2; ++m)
    #pragma unroll
    for (int q = 0; q < 4; ++q) {
      float l = lsum[m][q];
      l += __shfl_xor(l, 1);
      l += __shfl_xor(l, 2);
      l += __shfl_xor(l, 4);
      l += __shfl_xor(l, 8);
      const float inv = 1.f / l;     // >=1 unmasked entry (self-loop)
      const long rowg = (long)(b * NB + n0 + wid * 32 + m * 16 + kg * 4 + q);
      #pragma unroll
      for (int n = 0; n < 4; ++n) {
        const long idx = rowg * DMODEL + h * 64 + n * 16 + lx;
        ohi[idx] = f2b(o[m][n][q] * inv);
      }
    }
}

// ---------------------------------------------------------------------------
// Fused GRU + LayerNorm. gi bf16, gh bf16, h = hb_hi + hb_lo.
// ---------------------------------------------------------------------------
__global__ __launch_bounds__(256) void gru_ln_kernel(
    const u16* __restrict__ gi, const u16* __restrict__ gh,
    const u16* __restrict__ hhi, const u16* __restrict__ hlo,
    const float* __restrict__ ln_g, const float* __restrict__ ln_b,
    float* __restrict__ out)
{
  const long row = blockIdx.x;
  const int tid = threadIdx.x;
  const u16* gir = gi + row * 1536;
  const u16* ghr = gh + row * 1536;

  float val[2];
  float sum = 0.f, sq = 0.f;
  #pragma unroll
  for (int l = 0; l < 2; ++l) {
    int d = tid + l * 256;
    float r = 1.f / (1.f + __expf(-(b2f(gir[d]) + b2f(ghr[d]))));
    float z = 1.f / (1.f + __expf(-(b2f(gir[512 + d]) + b2f(ghr[512 + d]))));
    float n = tanhf(b2f(gir[1024 + d]) + r * b2f(ghr[1024 + d]));
    float hv = b2f(hhi[row * 512 + d]) + b2f(hlo[row * 512 + d]);
    float hn = (1.f - z) * n + z * hv;
    val[l] = hn; sum += hn; sq += hn * hn;
  }
  #pragma unroll
  for (int off = 32; off > 0; off >>= 1) {
    sum += __shfl_xor(sum, off);
    sq  += __shfl_xor(sq,  off);
  }
  __shared__ float s1[4], s2[4];
  if ((tid & 63) == 0) { s1[tid >> 6] = sum; s2[tid >> 6] = sq; }
  __syncthreads();
  sum = s1[0] + s1[1] + s1[2] + s1[3];
  sq  = s2[0] + s2[1] + s2[2] + s2[3];
  const float mu  = sum * (1.f / 512.f);
  float var = sq * (1.f / 512.f) - mu * mu;
  var = fmaxf(var, 0.f);
  const float inv = rsqrtf(var + 1e-5f);
  #pragma unroll
  for (int l = 0; l < 2; ++l) {
    int d = tid + l * 256;
    out[row * 512 + d] = (val[l] - mu) * inv * ln_g[d] + ln_b[d];
  }
}

// ---------------------------------------------------------------------------
extern "C" void kernel_launch(void* const* d_in, const int* in_sizes, int n_in,
                              void* d_out, int out_size, void* d_ws, size_t ws_size,
                              hipStream_t stream) {
  (void)in_sizes; (void)n_in; (void)out_size; (void)ws_size;
  const float* inputs   = (const float*)d_in[0];
  const float* memory   = (const float*)d_in[1];
  const int*   graph    = (const int*)  d_in[2];
  const float* w_head_w = (const float*)d_in[3];
  const float* w_head_b = (const float*)d_in[4];
  const float* w_tail_w = (const float*)d_in[5];
  const float* w_tail_b = (const float*)d_in[6];
  const float* w_info_w = (const float*)d_in[7];
  const float* w_info_b = (const float*)d_in[8];
  const float* w_comb_w = (const float*)d_in[9];
  const float* w_comb_b = (const float*)d_in[10];
  const float* gru_w_ih = (const float*)d_in[11];
  const float* gru_w_hh = (const float*)d_in[12];
  const float* gru_b_ih = (const float*)d_in[13];
  const float* gru_b_hh = (const float*)d_in[14];
  const float* ln_g     = (const float*)d_in[15];
  const float* ln_b     = (const float*)d_in[16];
  float* out = (float*)d_out;

  // ---- workspace layout (byte offsets, 112 MiB used; all bf16) ----
  char* W = (char*)d_ws;
  const size_t MB = 1u << 20;
  u16* in_bf   = (u16*)(W + 0 * MB);     // 8MB; live: head, gi GEMMs
  u16* mem_bf  = (u16*)(W + 8 * MB);     // 8MB; live: tail/info GEMMs
  u16* hb_hi   = mem_bf;                 // reuse after attn: comb out
  u16* hb_lo   = (u16*)(W + 16 * MB);    // 8MB
  u16* whB     = (u16*)(W + 24 * MB);    // weights 5MB: 24..29
  u16* wtB     = whB  + 262144;
  u16* wiB     = wtB  + 262144;
  u16* wcB     = wiB  + 262144;
  u16* wihB    = wcB  + 262144;
  u16* whhB    = wihB + 786432;
  unsigned* bitsW = (unsigned*)(W + 30 * MB);  // 1MB packed graph
  u16* head_bf = (u16*)(W + 32 * MB);    // 8MB, dead after attn
  u16* tail_bf = (u16*)(W + 40 * MB);    // 8MB, dead after attn
  u16* VtB     = (u16*)(W + 48 * MB);    // 8MB, dead after attn
  u16* attn_hi = (u16*)(W + 56 * MB);    // 8MB, dead after comb
  u16* giB     = (u16*)(W + 64 * MB);    // 24MB bf16 [8192][1536]
  u16* ghB     = (u16*)(W + 88 * MB);    // 24MB

  const dim3 blk(256);
  const float inv_scale = 0.04419417382415922f;  // 1/sqrt(512)

  // merged bf16 casts (1 launch) + mask pack
  cast_all<<<dim3(10752), blk, 0, stream>>>(
      inputs, memory, w_head_w, w_tail_w, w_info_w, w_comb_w, gru_w_ih, gru_w_hh,
      in_bf, mem_bf, whB, wtB, wiB, wcB, wihB, whhB);
  pack_graph<<<dim3(1024), blk, 0, stream>>>(graph, bitsW);

  // projections (1-pass bf16): head has 1/sqrt(D) folded; info -> transposed Vt
  gemm_mfma<1><<<dim3(8, 64), blk, 0, stream>>>(in_bf,  whB, w_head_b, head_bf, nullptr, inv_scale, 512);
  gemm_mfma<1><<<dim3(8, 64), blk, 0, stream>>>(mem_bf, wtB, w_tail_b, tail_bf, nullptr, 1.0f, 512);
  gemm_mfma<3><<<dim3(8, 64), blk, 0, stream>>>(mem_bf, wiB, w_info_b, VtB,     nullptr, 1.0f, 512);

  // MFMA flash attention -> bf16 output
  attn_mfma<<<dim3(8, 64), blk, 0, stream>>>(head_bf, tail_bf, VtB, bitsW, attn_hi);

  // comb -> hbuf (split hi/lo out preserves h through the z*h path)
  gemm_mfma<2><<<dim3(8, 64), blk, 0, stream>>>(attn_hi, wcB, w_comb_b, hb_hi, hb_lo, 1.0f, 512);

  // GRU gate GEMMs (both 1-pass bf16 out)
  gemm_mfma<1><<<dim3(24, 64), blk, 0, stream>>>(hb_hi, whhB, gru_b_hh, ghB, nullptr, 1.0f, 1536);
  gemm_mfma<1><<<dim3(24, 64), blk, 0, stream>>>(in_bf, wihB, gru_b_ih, giB, nullptr, 1.0f, 1536);

  // fused GRU + LayerNorm
  gru_ln_kernel<<<dim3(8192), blk, 0, stream>>>(giB, ghB, hb_hi, hb_lo, ln_g, ln_b, out);
}